// Round 1
// baseline (216.029 us; speedup 1.0000x reference)
//
#include <hip/hip_runtime.h>
#include <hip/hip_bf16.h>
#include <math.h>

#define BB 2
#define CC 128
#define HH 96
#define WW 96
#define HWX (HH*WW)        // 9216
#define KTOT (CC*9)        // 1152
#define OC 128
#define KHALF 576          // deform K split: 64 channels per half
#define ROWH 600           // 576 + 24 pad; 1200 B row stride (16B-aligned for b128 reads)
#define QC 32              // offsets: channels per block
#define PXB 16             // pixels per deform block (was 32): 1152 blocks, 23.8 KB LDS -> 6 blocks/CU

typedef __attribute__((ext_vector_type(8))) __bf16 bf16x8;
typedef __attribute__((ext_vector_type(4))) float floatx4;
typedef __attribute__((ext_vector_type(4))) unsigned int uintx4;

// ---------------- K0a: zero the offset accumulators (ws is poisoned 0xAA) -------------
__global__ __launch_bounds__(256) void zero_kernel(float* __restrict__ p, int n)
{
    int t = blockIdx.x * 256 + threadIdx.x;
    if (t < n) p[t] = 0.f;
}

// ---------------- K0b: repack pconv_w/adconv_w -> wrep[(c*9+tap)*24 + o] --------------
__global__ __launch_bounds__(256) void wrep_kernel(const float* __restrict__ pw,
                                                   const float* __restrict__ aw,
                                                   float* __restrict__ wrep)
{
    int t = blockIdx.x * 256 + threadIdx.x;    // 0..27647
    if (t >= KTOT * 24) return;
    int tapch = t / 24;
    int o = t - tapch * 24;
    float v = 0.f;
    if (o < 18)      v = pw[o * KTOT + tapch];
    else if (o < 21) v = aw[(o - 18) * KTOT + tapch];
    wrep[t] = v;
}

// ---------------- K0c: conv_w fp32 -> bf16 (same [o][k] layout), scalar stores --------
__global__ __launch_bounds__(256) void wbf_kernel(const float* __restrict__ w,
                                                  __bf16* __restrict__ wbf)
{
    int t = blockIdx.x * 256 + threadIdx.x;
    if (t < KTOT * OC) wbf[t] = (__bf16)w[t];
}

// ---------------- K1: offsets conv, c-quarter blocks, ALL operands in LDS -------------
// grid = BB*144*4, 512 thr = 8 waves x 4 channels each. Raw sums via atomicAdd.
__global__ __launch_bounds__(512) void offsets_kernel(
    const float* __restrict__ x, const float* __restrict__ wrep,
    float* __restrict__ offw, float* __restrict__ adw)
{
    __shared__ float sm[10112];   // [0,3200): xs[32][10][10]; [3200,10112): wl[32*9*24];
                                  // reduce phase aliases [0,9408)
    int blk = blockIdx.x;
    int cq = blk & 3;
    int rest = blk >> 2;
    int b = rest / 144;
    int t2 = rest % 144;
    int ti = t2 / 12, tj = t2 % 12;
    int i0 = ti * 8, j0 = tj * 8;
    int tid = threadIdx.x;
    float* xs = sm;
    float* wl = sm + 3200;

    for (int idx = tid; idx < 3200; idx += 512) {
        int cl = idx / 100; int r = idx % 100; int u = r / 10, v = r % 10;
        int gi = i0 + u - 1, gj = j0 + v - 1;
        float val = 0.f;
        if (gi >= 0 && gi < HH && gj >= 0 && gj < WW)
            val = x[((b * CC + cq * QC + cl) * HH + gi) * WW + gj];
        xs[idx] = val;
    }
    {   // weights: 32*9*24 = 6912 floats, coalesced float4
        const float4* src = (const float4*)(wrep + (size_t)(cq * QC) * 9 * 24);
        float4* dst = (float4*)wl;
        for (int idx = tid; idx < 1728; idx += 512) dst[idx] = src[idx];
    }
    __syncthreads();

    int wave = tid >> 6, lane = tid & 63;
    int pi = lane >> 3, pj = lane & 7;
    float acc[21];
#pragma unroll
    for (int o = 0; o < 21; ++o) acc[o] = 0.f;

    for (int cc = 0; cc < 4; ++cc) {
        int cl = wave * 4 + cc;
        const float* xr = &xs[cl * 100 + pi * 10 + pj];
        const float* wr = &wl[cl * 9 * 24];
#pragma unroll
        for (int di = 0; di < 3; ++di) {
#pragma unroll
            for (int dj = 0; dj < 3; ++dj) {
                int tap = di * 3 + dj;
                float xv = xr[di * 10 + dj];
                const float4* wp = (const float4*)(wr + tap * 24);
                float4 w0 = wp[0], w1 = wp[1], w2 = wp[2], w3 = wp[3], w4 = wp[4];
                float w20 = wr[tap * 24 + 20];
                acc[0]  += xv * w0.x; acc[1]  += xv * w0.y; acc[2]  += xv * w0.z; acc[3]  += xv * w0.w;
                acc[4]  += xv * w1.x; acc[5]  += xv * w1.y; acc[6]  += xv * w1.z; acc[7]  += xv * w1.w;
                acc[8]  += xv * w2.x; acc[9]  += xv * w2.y; acc[10] += xv * w2.z; acc[11] += xv * w2.w;
                acc[12] += xv * w3.x; acc[13] += xv * w3.y; acc[14] += xv * w3.z; acc[15] += xv * w3.w;
                acc[16] += xv * w4.x; acc[17] += xv * w4.y; acc[18] += xv * w4.z; acc[19] += xv * w4.w;
                acc[20] += xv * w20;
            }
        }
    }
    __syncthreads();                 // xs/wl dead; alias reduce buffer over sm
    if (wave > 0) {
        float* red = &sm[((wave - 1) * 64 + lane) * 21];
#pragma unroll
        for (int o = 0; o < 21; ++o) red[o] = acc[o];
    }
    __syncthreads();
    if (wave == 0) {
#pragma unroll
        for (int r = 0; r < 7; ++r) {
            const float* red = &sm[(r * 64 + lane) * 21];
#pragma unroll
            for (int o = 0; o < 21; ++o) acc[o] += red[o];
        }
        int i = i0 + pi, j = j0 + pj;
#pragma unroll
        for (int o = 0; o < 18; ++o)
            atomicAdd(&offw[((b * 18 + o) * HH + i) * WW + j], acc[o]);
#pragma unroll
        for (int o = 0; o < 3; ++o)
            atomicAdd(&adw[((b * 3 + o) * HH + i) * WW + j], acc[18 + o]);
    }
}

// ---------------- K2: sampling + MFMA GEMM, 16-px tiles for occupancy -----------------
// grid = BB*HWX/16 = 1152 blocks, 256 thr. LDS 23.8 KB -> 6 blocks/CU (24 waves/CU).
// Metadata phase folds OOB masks into zeroed weights + safe flat indices, so the hot
// gather loop is pure {4 loads, 4 FMA, cvt, ds_write} with 16 loads in flight per tap.
__global__ __launch_bounds__(256, 6) void deform_kernel(
    const float* __restrict__ x, const float* __restrict__ offw,
    const float* __restrict__ adw, const float* __restrict__ pb,
    const float* __restrict__ ab, const float* __restrict__ w,
    const __bf16* __restrict__ wbf, float* __restrict__ out)
{
    __shared__ __align__(16) __bf16 xoff[PXB * ROWH];   // 19200 B
    __shared__ int4   qidx[PXB * 9];                    // 2304 B: flat plane offsets (lt,rb,lb,rt)
    __shared__ float4 gwt[PXB * 9];                     // 2304 B: weights, zeroed when OOB

    int tid = threadIdx.x;
    int gid0 = blockIdx.x * PXB;
    int b  = gid0 / HWX;
    int r0 = gid0 - b * HWX;
    int i  = r0 / WW;
    int j0 = r0 % WW;

    if (tid < PXB * 9) {
        int t = tid;
        int px = t / 9, n = t % 9;
        int j = j0 + px;
        float offx = offw[((b * 18 + n) * HH + i) * WW + j] + pb[n];
        float offy = offw[((b * 18 + 9 + n) * HH + i) * WW + j] + pb[9 + n];
        float zad  = adw[((b * 3 + (n % 3)) * HH + i) * WW + j] + ab[n % 3];
        float ad   = 2.f * (1.f - 1.f / (1.f + expf(-zad)));
        float pnx = (float)(n / 3 - 1), pny = (float)(n % 3 - 1);
        float pxf = (float)(i + 1) + pnx * (1.f + ad) + offx;
        float pyf = (float)(j + 1) + pny * (1.f + ad) + offy;
        float flx = floorf(pxf), fly = floorf(pyf);
        float qltx = fminf(fmaxf(flx, 0.f), 97.f);
        float qlty = fminf(fmaxf(fly, 0.f), 97.f);
        float qrbx = fminf(fmaxf(flx + 1.f, 0.f), 97.f);
        float qrby = fminf(fmaxf(fly + 1.f, 0.f), 97.f);
        bool mx = (pxf < 1.f) || (pxf > 96.f);
        bool my = (pyf < 1.f) || (pyf > 96.f);
        float pxm = mx ? flx : pxf; pxm = fminf(fmaxf(pxm, 0.f), 97.f);
        float pym = my ? fly : pyf; pym = fminf(fmaxf(pym, 0.f), 97.f);
        float glt = (1.f + (qltx - pxm)) * (1.f + (qlty - pym));
        float grb = (1.f - (qrbx - pxm)) * (1.f - (qrby - pym));
        float glb = (1.f + (qltx - pxm)) * (1.f - (qrby - pym));
        float grt = (1.f - (qrbx - pxm)) * (1.f + (qlty - pym));
        int ilt = (int)qltx, jlt = (int)qlty, irb = (int)qrbx, jrb = (int)qrby;
        bool m_lt = (ilt >= 1) & (ilt <= 96) & (jlt >= 1) & (jlt <= 96);
        bool m_rb = (irb >= 1) & (irb <= 96) & (jrb >= 1) & (jrb <= 96);
        bool m_lb = (ilt >= 1) & (ilt <= 96) & (jrb >= 1) & (jrb <= 96);
        bool m_rt = (irb >= 1) & (irb <= 96) & (jlt >= 1) & (jlt <= 96);
        // folded OOB: weight 0 + safe index 0 == old (in-bounds ? x : 0) contribution
        qidx[t] = make_int4(m_lt ? (ilt - 1) * WW + (jlt - 1) : 0,
                            m_rb ? (irb - 1) * WW + (jrb - 1) : 0,
                            m_lb ? (ilt - 1) * WW + (jrb - 1) : 0,
                            m_rt ? (irb - 1) * WW + (jlt - 1) : 0);
        gwt[t]  = make_float4(m_lt ? glt : 0.f, m_rb ? grb : 0.f,
                              m_lb ? glb : 0.f, m_rt ? grt : 0.f);
    }
    __syncthreads();

    int wv = tid >> 6, lane = tid & 63;
    int quad = lane >> 4, l15 = lane & 15;
    int o0 = wv * 32 + l15;
    int o1 = o0 + 16;
    floatx4 acc0 = {0,0,0,0}, acc1 = {0,0,0,0};
    const float*  w0f = w   + (size_t)o0 * KTOT;
    const float*  w1f = w   + (size_t)o1 * KTOT;
    const __bf16* w0b = wbf + (size_t)o0 * KTOT;
    const __bf16* w1b = wbf + (size_t)o1 * KTOT;
    const float* xb = x + (size_t)b * CC * HWX;
    const __bf16* arow = &xoff[l15 * ROWH];
    bool ok = false;

    int gpx = tid & 15;                 // gather pixel: constant per thread
    int gs  = tid >> 4;                 // 0..15: channel start
    __bf16* grow = &xoff[gpx * ROWH];
    const int4*   qrow = &qidx[gpx * 9];
    const float4* grw  = &gwt[gpx * 9];

    for (int h = 0; h < 2; ++h) {
        const float* xc0 = xb + (size_t)(h * 64 + gs) * HWX;
        const float* xc1 = xc0 + (size_t)16 * HWX;
        const float* xc2 = xc1 + (size_t)16 * HWX;
        const float* xc3 = xc2 + (size_t)16 * HWX;
#pragma unroll 3
        for (int n = 0; n < 9; ++n) {
            int4 q = qrow[n];
            float4 g = grw[n];
            // corner order matches verified kernel: lt, rb, lb, rt
            float v0 = g.x * xc0[q.x] + g.y * xc0[q.y] + g.z * xc0[q.z] + g.w * xc0[q.w];
            float v1 = g.x * xc1[q.x] + g.y * xc1[q.y] + g.z * xc1[q.z] + g.w * xc1[q.w];
            float v2 = g.x * xc2[q.x] + g.y * xc2[q.y] + g.z * xc2[q.z] + g.w * xc2[q.w];
            float v3 = g.x * xc3[q.x] + g.y * xc3[q.y] + g.z * xc3[q.z] + g.w * xc3[q.w];
            grow[(gs +  0) * 9 + n] = (__bf16)v0;
            grow[(gs + 16) * 9 + n] = (__bf16)v1;
            grow[(gs + 32) * 9 + n] = (__bf16)v2;
            grow[(gs + 48) * 9 + n] = (__bf16)v3;
        }
        __syncthreads();

        if (h == 0) {
            // Self-check vector paths against scalar-assembled (bit-identical by constr.)
            bf16x8 av0 = *(const bf16x8*)(arow + quad * 8);
            bf16x8 bv0 = *(const bf16x8*)(w0b + quad * 8);
            bf16x8 bv1 = *(const bf16x8*)(w1b + quad * 8);
            bf16x8 as0, bs0, bs1;
#pragma unroll
            for (int jj = 0; jj < 8; ++jj) {
                as0[jj] = arow[quad * 8 + jj];
                bs0[jj] = (__bf16)w0f[quad * 8 + jj];
                bs1[jj] = (__bf16)w1f[quad * 8 + jj];
            }
            uintx4 x0 = __builtin_bit_cast(uintx4, av0) ^ __builtin_bit_cast(uintx4, as0);
            uintx4 x2 = __builtin_bit_cast(uintx4, bv0) ^ __builtin_bit_cast(uintx4, bs0);
            uintx4 x3 = __builtin_bit_cast(uintx4, bv1) ^ __builtin_bit_cast(uintx4, bs1);
            unsigned int d = (x0[0]|x0[1]|x0[2]|x0[3])
                           | (x2[0]|x2[1]|x2[2]|x2[3]) | (x3[0]|x3[1]|x3[2]|x3[3]);
            ok = (__ballot(d != 0u) == 0ULL);   // wave-uniform
        }

        if (ok) {
            for (int kt = 0; kt < 18; ++kt) {
                int kl = kt * 32 + quad * 8;
                int kg = h * KHALF + kl;
                bf16x8 a0 = *(const bf16x8*)(arow + kl);
                bf16x8 b0 = *(const bf16x8*)(w0b + kg);
                bf16x8 b1 = *(const bf16x8*)(w1b + kg);
                acc0 = __builtin_amdgcn_mfma_f32_16x16x32_bf16(a0, b0, acc0, 0, 0, 0);
                acc1 = __builtin_amdgcn_mfma_f32_16x16x32_bf16(a0, b1, acc1, 0, 0, 0);
            }
        } else {
            for (int kt = 0; kt < 18; ++kt) {        // verified round-6 body
                int kl = kt * 32 + quad * 8;
                int kg = h * KHALF + kl;
                bf16x8 a0, b0, b1;
#pragma unroll
                for (int jj = 0; jj < 8; ++jj) a0[jj] = arow[kl + jj];
                float4 wa0 = *(const float4*)(w0f + kg);
                float4 wb0 = *(const float4*)(w0f + kg + 4);
                float4 wa1 = *(const float4*)(w1f + kg);
                float4 wb1 = *(const float4*)(w1f + kg + 4);
                b0[0] = (__bf16)wa0.x; b0[1] = (__bf16)wa0.y; b0[2] = (__bf16)wa0.z; b0[3] = (__bf16)wa0.w;
                b0[4] = (__bf16)wb0.x; b0[5] = (__bf16)wb0.y; b0[6] = (__bf16)wb0.z; b0[7] = (__bf16)wb0.w;
                b1[0] = (__bf16)wa1.x; b1[1] = (__bf16)wa1.y; b1[2] = (__bf16)wa1.z; b1[3] = (__bf16)wa1.w;
                b1[4] = (__bf16)wb1.x; b1[5] = (__bf16)wb1.y; b1[6] = (__bf16)wb1.z; b1[7] = (__bf16)wb1.w;
                acc0 = __builtin_amdgcn_mfma_f32_16x16x32_bf16(a0, b0, acc0, 0, 0, 0);
                acc1 = __builtin_amdgcn_mfma_f32_16x16x32_bf16(a0, b1, acc1, 0, 0, 0);
            }
        }
        __syncthreads();
    }

#pragma unroll
    for (int rr = 0; rr < 4; ++rr) {
        int m0 = quad * 4 + rr;          // pixel row 0..15
        int ja = j0 + m0;
        out[((b * OC + o0) * HH + i) * WW + ja] = acc0[rr];
        out[((b * OC + o1) * HH + i) * WW + ja] = acc1[rr];
    }
}

extern "C" void kernel_launch(void* const* d_in, const int* in_sizes, int n_in,
                              void* d_out, int out_size, void* d_ws, size_t ws_size,
                              hipStream_t stream)
{
    const float* x  = (const float*)d_in[0];
    const float* cw = (const float*)d_in[1];
    const float* pw = (const float*)d_in[2];
    const float* pb = (const float*)d_in[3];
    const float* aw = (const float*)d_in[4];
    const float* ab = (const float*)d_in[5];
    float* out = (float*)d_out;

    char* ws = (char*)d_ws;
    float*  offw = (float*)ws;                      // 331776 fp32 (raw sums)
    float*  adw  = offw + BB * 18 * HWX;            // 55296 fp32
    float*  wrep = adw + BB * 3 * HWX;              // 27648 fp32
    __bf16* wbf  = (__bf16*)(wrep + KTOT * 24);     // 147456 bf16 (offset 16B-aligned)

    int nzero = BB * 21 * HWX;
    zero_kernel<<<(nzero + 255) / 256, 256, 0, stream>>>(offw, nzero);
    wrep_kernel<<<(KTOT * 24 + 255) / 256, 256, 0, stream>>>(pw, aw, wrep);
    wbf_kernel<<<(KTOT * OC + 255) / 256, 256, 0, stream>>>(cw, wbf);
    offsets_kernel<<<BB * 144 * 4, 512, 0, stream>>>(x, wrep, offw, adw);
    deform_kernel<<<(BB * HWX) / PXB, 256, 0, stream>>>(x, offw, adw, pb, ab, cw, wbf, out);
}

// Round 2
// 202.959 us; speedup vs baseline: 1.0644x; 1.0644x over previous
//
#include <hip/hip_runtime.h>
#include <hip/hip_bf16.h>
#include <math.h>

#define BB 2
#define CC 128
#define HH 96
#define WW 96
#define HWX (HH*WW)        // 9216
#define KTOT (CC*9)        // 1152
#define OC 128
#define KHALF 576          // deform K split: 64 channels per half
#define ROWH 600           // 576 + 24 pad; 1200 B row stride (16B-aligned for b128 reads)
#define QC 32              // offsets: channels per block
#define PXB 16             // pixels per deform block

typedef __attribute__((ext_vector_type(8))) __bf16 bf16x8;
typedef __attribute__((ext_vector_type(4))) __bf16 bf16x4;
typedef __attribute__((ext_vector_type(4))) float floatx4;

// ---------------- K0a: repack pconv_w/adconv_w -> wrep[(c*9+tap)*24 + o] --------------
__global__ __launch_bounds__(256) void wrep_kernel(const float* __restrict__ pw,
                                                   const float* __restrict__ aw,
                                                   float* __restrict__ wrep)
{
    int t = blockIdx.x * 256 + threadIdx.x;    // 0..27647
    if (t >= KTOT * 24) return;
    int tapch = t / 24;
    int o = t - tapch * 24;
    float v = 0.f;
    if (o < 18)      v = pw[o * KTOT + tapch];
    else if (o < 21) v = aw[(o - 18) * KTOT + tapch];
    wrep[t] = v;
}

// ---------------- K0b: conv_w fp32 -> bf16 in k'-permuted layout ----------------------
// k' = h*576 + tap*64 + cl  maps to original k = (h*64+cl)*9 + tap.
// A (LDS xoff) uses the same permutation, so the GEMM is unchanged up to f32 sum order.
__global__ __launch_bounds__(256) void wbf_kernel(const float* __restrict__ w,
                                                  __bf16* __restrict__ wbf)
{
    int t = blockIdx.x * 256 + threadIdx.x;
    if (t >= KTOT * OC) return;
    int o  = t / KTOT;
    int kp = t - o * KTOT;
    int h  = kp / KHALF;
    int r  = kp - h * KHALF;
    int n  = r >> 6;
    int cl = r & 63;
    int c  = h * 64 + cl;
    wbf[t] = (__bf16)w[(size_t)o * KTOT + c * 9 + n];
}

// ---------------- K0c: x NCHW -> NHWC (xT[((b*96+i)*96+j)*128 + c]) -------------------
__global__ __launch_bounds__(256) void xt_kernel(const float* __restrict__ x,
                                                 float* __restrict__ xT)
{
    __shared__ float tile[96 * 129];   // [j][c], +1 col pad -> conflict-free both phases
    int blk = blockIdx.x;              // b*96 + i
    int b = blk / HH, i = blk % HH;
    int tid = threadIdx.x;
    const float* src = x + (size_t)b * CC * HWX + (size_t)i * WW;
    for (int idx = tid; idx < CC * WW; idx += 256) {
        int c = idx / WW, j = idx - c * WW;
        tile[j * 129 + c] = src[(size_t)c * HWX + j];
    }
    __syncthreads();
    float* dst = xT + ((size_t)b * HWX + (size_t)i * WW) * CC;
    for (int idx = tid; idx < CC * WW; idx += 256) {
        int j = idx >> 7, c = idx & 127;
        dst[idx] = tile[j * 129 + c];
    }
}

// ---------------- K1: offsets conv, c-quarter blocks, partial-sum outputs -------------
// grid = BB*144*4, 512 thr. Writes per-quarter partials (no atomics, no zero pass);
// deform's metadata phase sums the 4 partials.
__global__ __launch_bounds__(512) void offsets_kernel(
    const float* __restrict__ x, const float* __restrict__ wrep,
    float* __restrict__ offp, float* __restrict__ adp)
{
    __shared__ float sm[10112];   // [0,3200): xs[32][10][10]; [3200,10112): wl[32*9*24];
                                  // reduce phase aliases [0,9408)
    int blk = blockIdx.x;
    int cq = blk & 3;
    int rest = blk >> 2;
    int b = rest / 144;
    int t2 = rest % 144;
    int ti = t2 / 12, tj = t2 % 12;
    int i0 = ti * 8, j0 = tj * 8;
    int tid = threadIdx.x;
    float* xs = sm;
    float* wl = sm + 3200;

    for (int idx = tid; idx < 3200; idx += 512) {
        int cl = idx / 100; int r = idx % 100; int u = r / 10, v = r % 10;
        int gi = i0 + u - 1, gj = j0 + v - 1;
        float val = 0.f;
        if (gi >= 0 && gi < HH && gj >= 0 && gj < WW)
            val = x[((b * CC + cq * QC + cl) * HH + gi) * WW + gj];
        xs[idx] = val;
    }
    {   // weights: 32*9*24 = 6912 floats, coalesced float4
        const float4* src = (const float4*)(wrep + (size_t)(cq * QC) * 9 * 24);
        float4* dst = (float4*)wl;
        for (int idx = tid; idx < 1728; idx += 512) dst[idx] = src[idx];
    }
    __syncthreads();

    int wave = tid >> 6, lane = tid & 63;
    int pi = lane >> 3, pj = lane & 7;
    float acc[21];
#pragma unroll
    for (int o = 0; o < 21; ++o) acc[o] = 0.f;

    for (int cc = 0; cc < 4; ++cc) {
        int cl = wave * 4 + cc;
        const float* xr = &xs[cl * 100 + pi * 10 + pj];
        const float* wr = &wl[cl * 9 * 24];
#pragma unroll
        for (int di = 0; di < 3; ++di) {
#pragma unroll
            for (int dj = 0; dj < 3; ++dj) {
                int tap = di * 3 + dj;
                float xv = xr[di * 10 + dj];
                const float4* wp = (const float4*)(wr + tap * 24);
                float4 w0 = wp[0], w1 = wp[1], w2 = wp[2], w3 = wp[3], w4 = wp[4];
                float w20 = wr[tap * 24 + 20];
                acc[0]  += xv * w0.x; acc[1]  += xv * w0.y; acc[2]  += xv * w0.z; acc[3]  += xv * w0.w;
                acc[4]  += xv * w1.x; acc[5]  += xv * w1.y; acc[6]  += xv * w1.z; acc[7]  += xv * w1.w;
                acc[8]  += xv * w2.x; acc[9]  += xv * w2.y; acc[10] += xv * w2.z; acc[11] += xv * w2.w;
                acc[12] += xv * w3.x; acc[13] += xv * w3.y; acc[14] += xv * w3.z; acc[15] += xv * w3.w;
                acc[16] += xv * w4.x; acc[17] += xv * w4.y; acc[18] += xv * w4.z; acc[19] += xv * w4.w;
                acc[20] += xv * w20;
            }
        }
    }
    __syncthreads();                 // xs/wl dead; alias reduce buffer over sm
    if (wave > 0) {
        float* red = &sm[((wave - 1) * 64 + lane) * 21];
#pragma unroll
        for (int o = 0; o < 21; ++o) red[o] = acc[o];
    }
    __syncthreads();
    if (wave == 0) {
#pragma unroll
        for (int r = 0; r < 7; ++r) {
            const float* red = &sm[(r * 64 + lane) * 21];
#pragma unroll
            for (int o = 0; o < 21; ++o) acc[o] += red[o];
        }
        int i = i0 + pi, j = j0 + pj;
        int ij = i * WW + j;
        float* op = offp + (size_t)((b * 4 + cq) * 18) * HWX + ij;
#pragma unroll
        for (int o = 0; o < 18; ++o) op[(size_t)o * HWX] = acc[o];
        float* ap = adp + (size_t)((b * 4 + cq) * 3) * HWX + ij;
#pragma unroll
        for (int o = 0; o < 3; ++o) ap[(size_t)o * HWX] = acc[18 + o];
    }
}

// ---------------- K2: sampling (NHWC float4 gathers) + MFMA GEMM ----------------------
// grid = 1152 blocks, 256 thr. Gather: thread = (pixel, 4-channel group); one corner =
// one aligned float4; a wave's 4 channel-groups consume one full 64B line per pixel.
// LDS xoff row layout per half: k' = tap*64 + cl  (matches wbf k' permutation).
__global__ __launch_bounds__(256, 4) void deform_kernel(
    const float* __restrict__ xT, const float* __restrict__ offp,
    const float* __restrict__ adp, const float* __restrict__ pb,
    const float* __restrict__ ab, const __bf16* __restrict__ wbf,
    float* __restrict__ out)
{
    __shared__ __align__(16) __bf16 xoff[PXB * ROWH];   // 19200 B
    __shared__ int4   qidx[PXB * 9];                    // flat plane offsets (lt,rb,lb,rt)
    __shared__ float4 gwt[PXB * 9];                     // weights, zeroed when OOB

    int tid = threadIdx.x;
    int gid0 = blockIdx.x * PXB;
    int b  = gid0 / HWX;
    int r0 = gid0 - b * HWX;
    int i  = r0 / WW;
    int j0 = r0 % WW;

    if (tid < PXB * 9) {
        int t = tid;
        int px = t / 9, n = t % 9;
        int j = j0 + px;
        int ij = i * WW + j;
        float offx = pb[n], offy = pb[9 + n], zad = ab[n % 3];
#pragma unroll
        for (int cq = 0; cq < 4; ++cq) {
            const float* op = offp + (size_t)((b * 4 + cq) * 18) * HWX + ij;
            offx += op[(size_t)n * HWX];
            offy += op[(size_t)(9 + n) * HWX];
            zad  += adp[(size_t)((b * 4 + cq) * 3 + (n % 3)) * HWX + ij];
        }
        float ad   = 2.f * (1.f - 1.f / (1.f + expf(-zad)));
        float pnx = (float)(n / 3 - 1), pny = (float)(n % 3 - 1);
        float pxf = (float)(i + 1) + pnx * (1.f + ad) + offx;
        float pyf = (float)(j + 1) + pny * (1.f + ad) + offy;
        float flx = floorf(pxf), fly = floorf(pyf);
        float qltx = fminf(fmaxf(flx, 0.f), 97.f);
        float qlty = fminf(fmaxf(fly, 0.f), 97.f);
        float qrbx = fminf(fmaxf(flx + 1.f, 0.f), 97.f);
        float qrby = fminf(fmaxf(fly + 1.f, 0.f), 97.f);
        bool mx = (pxf < 1.f) || (pxf > 96.f);
        bool my = (pyf < 1.f) || (pyf > 96.f);
        float pxm = mx ? flx : pxf; pxm = fminf(fmaxf(pxm, 0.f), 97.f);
        float pym = my ? fly : pyf; pym = fminf(fmaxf(pym, 0.f), 97.f);
        float glt = (1.f + (qltx - pxm)) * (1.f + (qlty - pym));
        float grb = (1.f - (qrbx - pxm)) * (1.f - (qrby - pym));
        float glb = (1.f + (qltx - pxm)) * (1.f - (qrby - pym));
        float grt = (1.f - (qrbx - pxm)) * (1.f + (qlty - pym));
        int ilt = (int)qltx, jlt = (int)qlty, irb = (int)qrbx, jrb = (int)qrby;
        bool m_lt = (ilt >= 1) & (ilt <= 96) & (jlt >= 1) & (jlt <= 96);
        bool m_rb = (irb >= 1) & (irb <= 96) & (jrb >= 1) & (jrb <= 96);
        bool m_lb = (ilt >= 1) & (ilt <= 96) & (jrb >= 1) & (jrb <= 96);
        bool m_rt = (irb >= 1) & (irb <= 96) & (jlt >= 1) & (jlt <= 96);
        // folded OOB: weight 0 + safe index 0 == (in-bounds ? x : 0) contribution
        qidx[t] = make_int4(m_lt ? (ilt - 1) * WW + (jlt - 1) : 0,
                            m_rb ? (irb - 1) * WW + (jrb - 1) : 0,
                            m_lb ? (ilt - 1) * WW + (jrb - 1) : 0,
                            m_rt ? (irb - 1) * WW + (jlt - 1) : 0);
        gwt[t]  = make_float4(m_lt ? glt : 0.f, m_rb ? grb : 0.f,
                              m_lb ? glb : 0.f, m_rt ? grt : 0.f);
    }
    __syncthreads();

    int wv = tid >> 6, lane = tid & 63;
    int quad = lane >> 4, l15 = lane & 15;
    int o0 = wv * 32 + l15;
    int o1 = o0 + 16;
    floatx4 acc0 = {0,0,0,0}, acc1 = {0,0,0,0};
    const __bf16* w0b = wbf + (size_t)o0 * KTOT;
    const __bf16* w1b = wbf + (size_t)o1 * KTOT;
    const __bf16* arow = &xoff[l15 * ROWH];

    int gpx = tid & 15;                 // gather pixel
    int gs  = tid >> 4;                 // 0..15: 4-channel group
    __bf16* grow = &xoff[gpx * ROWH];
    const int4*   qrow = &qidx[gpx * 9];
    const float4* grw  = &gwt[gpx * 9];
    const float* xb = xT + (size_t)b * HWX * CC + gs * 4;

    for (int h = 0; h < 2; ++h) {
        const float* xh = xb + h * 64;
#pragma unroll 3
        for (int n = 0; n < 9; ++n) {
            int4 q = qrow[n];
            float4 g = grw[n];
            float4 vlt = *(const float4*)(xh + (size_t)q.x * CC);
            float4 vrb = *(const float4*)(xh + (size_t)q.y * CC);
            float4 vlb = *(const float4*)(xh + (size_t)q.z * CC);
            float4 vrt = *(const float4*)(xh + (size_t)q.w * CC);
            bf16x4 o;   // same per-channel expression as verified kernel: lt,rb,lb,rt
            o[0] = (__bf16)(g.x * vlt.x + g.y * vrb.x + g.z * vlb.x + g.w * vrt.x);
            o[1] = (__bf16)(g.x * vlt.y + g.y * vrb.y + g.z * vlb.y + g.w * vrt.y);
            o[2] = (__bf16)(g.x * vlt.z + g.y * vrb.z + g.z * vlb.z + g.w * vrt.z);
            o[3] = (__bf16)(g.x * vlt.w + g.y * vrb.w + g.z * vlb.w + g.w * vrt.w);
            *(bf16x4*)(grow + n * 64 + gs * 4) = o;   // k' = tap*64 + cl, 8B store
        }
        __syncthreads();

        const __bf16* wb0 = w0b + h * KHALF;
        const __bf16* wb1 = w1b + h * KHALF;
        for (int kt = 0; kt < 18; ++kt) {
            int kl = kt * 32 + quad * 8;
            bf16x8 a0 = *(const bf16x8*)(arow + kl);
            bf16x8 b0 = *(const bf16x8*)(wb0 + kl);
            bf16x8 b1 = *(const bf16x8*)(wb1 + kl);
            acc0 = __builtin_amdgcn_mfma_f32_16x16x32_bf16(a0, b0, acc0, 0, 0, 0);
            acc1 = __builtin_amdgcn_mfma_f32_16x16x32_bf16(a0, b1, acc1, 0, 0, 0);
        }
        __syncthreads();
    }

#pragma unroll
    for (int rr = 0; rr < 4; ++rr) {
        int m0 = quad * 4 + rr;          // pixel 0..15
        int ja = j0 + m0;
        out[((b * OC + o0) * HH + i) * WW + ja] = acc0[rr];
        out[((b * OC + o1) * HH + i) * WW + ja] = acc1[rr];
    }
}

extern "C" void kernel_launch(void* const* d_in, const int* in_sizes, int n_in,
                              void* d_out, int out_size, void* d_ws, size_t ws_size,
                              hipStream_t stream)
{
    const float* x  = (const float*)d_in[0];
    const float* cw = (const float*)d_in[1];
    const float* pw = (const float*)d_in[2];
    const float* pb = (const float*)d_in[3];
    const float* aw = (const float*)d_in[4];
    const float* ab = (const float*)d_in[5];
    float* out = (float*)d_out;

    char* ws = (char*)d_ws;
    float*  offp = (float*)ws;                        // 2*4*18*9216 = 663552 fp32
    float*  adp  = offp + BB * 4 * 18 * HWX;          // 2*4*3*9216  = 221184 fp32
    float*  wrep = adp + BB * 4 * 3 * HWX;            // 27648 fp32
    __bf16* wbf  = (__bf16*)(wrep + KTOT * 24);       // 147456 bf16 (16B-aligned)
    float*  xT   = (float*)(wbf + (size_t)KTOT * OC); // 2359296 fp32 (16B-aligned)
    // total ws use: ~13.4 MB

    wrep_kernel<<<(KTOT * 24 + 255) / 256, 256, 0, stream>>>(pw, aw, wrep);
    wbf_kernel<<<(KTOT * OC + 255) / 256, 256, 0, stream>>>(cw, wbf);
    xt_kernel<<<BB * HH, 256, 0, stream>>>(x, xT);
    offsets_kernel<<<BB * 144 * 4, 512, 0, stream>>>(x, wrep, offp, adp);
    deform_kernel<<<(BB * HWX) / PXB, 256, 0, stream>>>(xT, offp, adp, pb, ab, wbf, out);
}

// Round 3
// 195.156 us; speedup vs baseline: 1.1070x; 1.0400x over previous
//
#include <hip/hip_runtime.h>
#include <hip/hip_bf16.h>
#include <math.h>

#define BB 2
#define CC 128
#define HH 96
#define WW 96
#define HWX (HH*WW)        // 9216
#define KTOT (CC*9)        // 1152
#define OC 128
#define KHALF 576          // deform K split: 64 channels per half
#define ROWH 600           // 576 + 24 pad; 1200 B row stride (16B-aligned for b128 reads)
#define QC 32              // offsets: channels per block
#define PXB 16             // pixels per deform block
#define NWG (BB*HWX/PXB)   // 1152 deform blocks

typedef __attribute__((ext_vector_type(8))) __bf16 bf16x8;
typedef __attribute__((ext_vector_type(4))) __bf16 bf16x4;
typedef __attribute__((ext_vector_type(4))) float floatx4;

// ---------------- K0a: repack pconv_w/adconv_w -> wrep[(c*9+tap)*24 + o] --------------
__global__ __launch_bounds__(256) void wrep_kernel(const float* __restrict__ pw,
                                                   const float* __restrict__ aw,
                                                   float* __restrict__ wrep)
{
    int t = blockIdx.x * 256 + threadIdx.x;    // 0..27647
    if (t >= KTOT * 24) return;
    int tapch = t / 24;
    int o = t - tapch * 24;
    float v = 0.f;
    if (o < 18)      v = pw[o * KTOT + tapch];
    else if (o < 21) v = aw[(o - 18) * KTOT + tapch];
    wrep[t] = v;
}

// ---------------- K0b: conv_w fp32 -> bf16 in k'-permuted layout ----------------------
// k' = h*576 + tap*64 + cl  maps to original k = (h*64+cl)*9 + tap.
// A (LDS xoff) uses the same permutation, so the GEMM is unchanged up to f32 sum order.
__global__ __launch_bounds__(256) void wbf_kernel(const float* __restrict__ w,
                                                  __bf16* __restrict__ wbf)
{
    int t = blockIdx.x * 256 + threadIdx.x;
    if (t >= KTOT * OC) return;
    int o  = t / KTOT;
    int kp = t - o * KTOT;
    int h  = kp / KHALF;
    int r  = kp - h * KHALF;
    int n  = r >> 6;
    int cl = r & 63;
    int c  = h * 64 + cl;
    wbf[t] = (__bf16)w[(size_t)o * KTOT + c * 9 + n];
}

// ---------------- K0c: x NCHW -> NHWC (xT[((b*96+i)*96+j)*128 + c]) -------------------
__global__ __launch_bounds__(256) void xt_kernel(const float* __restrict__ x,
                                                 float* __restrict__ xT)
{
    __shared__ float tile[96 * 129];   // [j][c], +1 col pad -> conflict-free both phases
    int blk = blockIdx.x;              // b*96 + i
    int b = blk / HH, i = blk % HH;
    int tid = threadIdx.x;
    const float* src = x + (size_t)b * CC * HWX + (size_t)i * WW;
    for (int idx = tid; idx < CC * WW; idx += 256) {
        int c = idx / WW, j = idx - c * WW;
        tile[j * 129 + c] = src[(size_t)c * HWX + j];
    }
    __syncthreads();
    float* dst = xT + ((size_t)b * HWX + (size_t)i * WW) * CC;
    for (int idx = tid; idx < CC * WW; idx += 256) {
        int j = idx >> 7, c = idx & 127;
        dst[idx] = tile[j * 129 + c];
    }
}

// ---------------- K1: offsets conv, c-quarter blocks, partial-sum outputs -------------
// grid = BB*144*4, 512 thr. Writes per-quarter partials (no atomics, no zero pass);
// deform's metadata phase sums the 4 partials.
__global__ __launch_bounds__(512) void offsets_kernel(
    const float* __restrict__ x, const float* __restrict__ wrep,
    float* __restrict__ offp, float* __restrict__ adp)
{
    __shared__ float sm[10112];   // [0,3200): xs[32][10][10]; [3200,10112): wl[32*9*24];
                                  // reduce phase aliases [0,9408)
    int blk = blockIdx.x;
    int cq = blk & 3;
    int rest = blk >> 2;
    int b = rest / 144;
    int t2 = rest % 144;
    int ti = t2 / 12, tj = t2 % 12;
    int i0 = ti * 8, j0 = tj * 8;
    int tid = threadIdx.x;
    float* xs = sm;
    float* wl = sm + 3200;

    for (int idx = tid; idx < 3200; idx += 512) {
        int cl = idx / 100; int r = idx % 100; int u = r / 10, v = r % 10;
        int gi = i0 + u - 1, gj = j0 + v - 1;
        float val = 0.f;
        if (gi >= 0 && gi < HH && gj >= 0 && gj < WW)
            val = x[((b * CC + cq * QC + cl) * HH + gi) * WW + gj];
        xs[idx] = val;
    }
    {   // weights: 32*9*24 = 6912 floats, coalesced float4
        const float4* src = (const float4*)(wrep + (size_t)(cq * QC) * 9 * 24);
        float4* dst = (float4*)wl;
        for (int idx = tid; idx < 1728; idx += 512) dst[idx] = src[idx];
    }
    __syncthreads();

    int wave = tid >> 6, lane = tid & 63;
    int pi = lane >> 3, pj = lane & 7;
    float acc[21];
#pragma unroll
    for (int o = 0; o < 21; ++o) acc[o] = 0.f;

    for (int cc = 0; cc < 4; ++cc) {
        int cl = wave * 4 + cc;
        const float* xr = &xs[cl * 100 + pi * 10 + pj];
        const float* wr = &wl[cl * 9 * 24];
#pragma unroll
        for (int di = 0; di < 3; ++di) {
#pragma unroll
            for (int dj = 0; dj < 3; ++dj) {
                int tap = di * 3 + dj;
                float xv = xr[di * 10 + dj];
                const float4* wp = (const float4*)(wr + tap * 24);
                float4 w0 = wp[0], w1 = wp[1], w2 = wp[2], w3 = wp[3], w4 = wp[4];
                float w20 = wr[tap * 24 + 20];
                acc[0]  += xv * w0.x; acc[1]  += xv * w0.y; acc[2]  += xv * w0.z; acc[3]  += xv * w0.w;
                acc[4]  += xv * w1.x; acc[5]  += xv * w1.y; acc[6]  += xv * w1.z; acc[7]  += xv * w1.w;
                acc[8]  += xv * w2.x; acc[9]  += xv * w2.y; acc[10] += xv * w2.z; acc[11] += xv * w2.w;
                acc[12] += xv * w3.x; acc[13] += xv * w3.y; acc[14] += xv * w3.z; acc[15] += xv * w3.w;
                acc[16] += xv * w4.x; acc[17] += xv * w4.y; acc[18] += xv * w4.z; acc[19] += xv * w4.w;
                acc[20] += xv * w20;
            }
        }
    }
    __syncthreads();                 // xs/wl dead; alias reduce buffer over sm
    if (wave > 0) {
        float* red = &sm[((wave - 1) * 64 + lane) * 21];
#pragma unroll
        for (int o = 0; o < 21; ++o) red[o] = acc[o];
    }
    __syncthreads();
    if (wave == 0) {
#pragma unroll
        for (int r = 0; r < 7; ++r) {
            const float* red = &sm[(r * 64 + lane) * 21];
#pragma unroll
            for (int o = 0; o < 21; ++o) acc[o] += red[o];
        }
        int i = i0 + pi, j = j0 + pj;
        int ij = i * WW + j;
        float* op = offp + (size_t)((b * 4 + cq) * 18) * HWX + ij;
#pragma unroll
        for (int o = 0; o < 18; ++o) op[(size_t)o * HWX] = acc[o];
        float* ap = adp + (size_t)((b * 4 + cq) * 3) * HWX + ij;
#pragma unroll
        for (int o = 0; o < 3; ++o) ap[(size_t)o * HWX] = acc[18 + o];
    }
}

// ---------------- K2: sampling (NHWC float4 gathers) + MFMA GEMM ----------------------
// grid = 1152 blocks, 256 thr. XCD-swizzled: logical = (wg&7)*144 + wg>>3, so each XCD
// owns a contiguous 24-row image slab (~1.2 MB working set, fits the 4 MB per-XCD L2).
// Gather: thread = (pixel, 4-channel group); one corner = one aligned float4; a wave's
// 4 channel-groups consume one full 64B line per pixel. Full tap unroll for load MLP.
__global__ __launch_bounds__(256, 4) void deform_kernel(
    const float* __restrict__ xT, const float* __restrict__ offp,
    const float* __restrict__ adp, const float* __restrict__ pb,
    const float* __restrict__ ab, const __bf16* __restrict__ wbf,
    float* __restrict__ out)
{
    __shared__ __align__(16) __bf16 xoff[PXB * ROWH];   // 19200 B
    __shared__ int4   qidx[PXB * 9];                    // flat plane offsets (lt,rb,lb,rt)
    __shared__ float4 gwt[PXB * 9];                     // weights, zeroed when OOB

    int tid = threadIdx.x;
    // XCD-aware swizzle: contiguous slab per XCD (NWG % 8 == 0 -> bijective)
    int lb = (blockIdx.x & 7) * (NWG >> 3) + (blockIdx.x >> 3);
    int gid0 = lb * PXB;
    int b  = gid0 / HWX;
    int r0 = gid0 - b * HWX;
    int i  = r0 / WW;
    int j0 = r0 % WW;

    if (tid < PXB * 9) {
        int t = tid;
        int px = t / 9, n = t % 9;
        int j = j0 + px;
        int ij = i * WW + j;
        float offx = pb[n], offy = pb[9 + n], zad = ab[n % 3];
#pragma unroll
        for (int cq = 0; cq < 4; ++cq) {
            const float* op = offp + (size_t)((b * 4 + cq) * 18) * HWX + ij;
            offx += op[(size_t)n * HWX];
            offy += op[(size_t)(9 + n) * HWX];
            zad  += adp[(size_t)((b * 4 + cq) * 3 + (n % 3)) * HWX + ij];
        }
        float ad   = 2.f * (1.f - 1.f / (1.f + expf(-zad)));
        float pnx = (float)(n / 3 - 1), pny = (float)(n % 3 - 1);
        float pxf = (float)(i + 1) + pnx * (1.f + ad) + offx;
        float pyf = (float)(j + 1) + pny * (1.f + ad) + offy;
        float flx = floorf(pxf), fly = floorf(pyf);
        float qltx = fminf(fmaxf(flx, 0.f), 97.f);
        float qlty = fminf(fmaxf(fly, 0.f), 97.f);
        float qrbx = fminf(fmaxf(flx + 1.f, 0.f), 97.f);
        float qrby = fminf(fmaxf(fly + 1.f, 0.f), 97.f);
        bool mx = (pxf < 1.f) || (pxf > 96.f);
        bool my = (pyf < 1.f) || (pyf > 96.f);
        float pxm = mx ? flx : pxf; pxm = fminf(fmaxf(pxm, 0.f), 97.f);
        float pym = my ? fly : pyf; pym = fminf(fmaxf(pym, 0.f), 97.f);
        float glt = (1.f + (qltx - pxm)) * (1.f + (qlty - pym));
        float grb = (1.f - (qrbx - pxm)) * (1.f - (qrby - pym));
        float glb = (1.f + (qltx - pxm)) * (1.f - (qrby - pym));
        float grt = (1.f - (qrbx - pxm)) * (1.f + (qlty - pym));
        int ilt = (int)qltx, jlt = (int)qlty, irb = (int)qrbx, jrb = (int)qrby;
        bool m_lt = (ilt >= 1) & (ilt <= 96) & (jlt >= 1) & (jlt <= 96);
        bool m_rb = (irb >= 1) & (irb <= 96) & (jrb >= 1) & (jrb <= 96);
        bool m_lb = (ilt >= 1) & (ilt <= 96) & (jrb >= 1) & (jrb <= 96);
        bool m_rt = (irb >= 1) & (irb <= 96) & (jlt >= 1) & (jlt <= 96);
        // folded OOB: weight 0 + safe index 0 == (in-bounds ? x : 0) contribution
        qidx[t] = make_int4(m_lt ? (ilt - 1) * WW + (jlt - 1) : 0,
                            m_rb ? (irb - 1) * WW + (jrb - 1) : 0,
                            m_lb ? (ilt - 1) * WW + (jrb - 1) : 0,
                            m_rt ? (irb - 1) * WW + (jlt - 1) : 0);
        gwt[t]  = make_float4(m_lt ? glt : 0.f, m_rb ? grb : 0.f,
                              m_lb ? glb : 0.f, m_rt ? grt : 0.f);
    }
    __syncthreads();

    int wv = tid >> 6, lane = tid & 63;
    int quad = lane >> 4, l15 = lane & 15;
    int o0 = wv * 32 + l15;
    int o1 = o0 + 16;
    floatx4 acc0 = {0,0,0,0}, acc1 = {0,0,0,0};
    const __bf16* w0b = wbf + (size_t)o0 * KTOT;
    const __bf16* w1b = wbf + (size_t)o1 * KTOT;
    const __bf16* arow = &xoff[l15 * ROWH];

    int gpx = tid & 15;                 // gather pixel
    int gs  = tid >> 4;                 // 0..15: 4-channel group
    __bf16* grow = &xoff[gpx * ROWH];
    const int4*   qrow = &qidx[gpx * 9];
    const float4* grw  = &gwt[gpx * 9];
    const float* xb = xT + (size_t)b * HWX * CC + gs * 4;

    for (int h = 0; h < 2; ++h) {
        const float* xh = xb + h * 64;
#pragma unroll
        for (int n = 0; n < 9; ++n) {
            int4 q = qrow[n];
            float4 g = grw[n];
            float4 vlt = *(const float4*)(xh + (size_t)q.x * CC);
            float4 vrb = *(const float4*)(xh + (size_t)q.y * CC);
            float4 vlb = *(const float4*)(xh + (size_t)q.z * CC);
            float4 vrt = *(const float4*)(xh + (size_t)q.w * CC);
            bf16x4 o;   // same per-channel expression as verified kernel: lt,rb,lb,rt
            o[0] = (__bf16)(g.x * vlt.x + g.y * vrb.x + g.z * vlb.x + g.w * vrt.x);
            o[1] = (__bf16)(g.x * vlt.y + g.y * vrb.y + g.z * vlb.y + g.w * vrt.y);
            o[2] = (__bf16)(g.x * vlt.z + g.y * vrb.z + g.z * vlb.z + g.w * vrt.z);
            o[3] = (__bf16)(g.x * vlt.w + g.y * vrb.w + g.z * vlb.w + g.w * vrt.w);
            *(bf16x4*)(grow + n * 64 + gs * 4) = o;   // k' = tap*64 + cl, 8B store
        }
        __syncthreads();

        const __bf16* wb0 = w0b + h * KHALF;
        const __bf16* wb1 = w1b + h * KHALF;
        for (int kt = 0; kt < 18; ++kt) {
            int kl = kt * 32 + quad * 8;
            bf16x8 a0 = *(const bf16x8*)(arow + kl);
            bf16x8 b0 = *(const bf16x8*)(wb0 + kl);
            bf16x8 b1 = *(const bf16x8*)(wb1 + kl);
            acc0 = __builtin_amdgcn_mfma_f32_16x16x32_bf16(a0, b0, acc0, 0, 0, 0);
            acc1 = __builtin_amdgcn_mfma_f32_16x16x32_bf16(a0, b1, acc1, 0, 0, 0);
        }
        __syncthreads();
    }

#pragma unroll
    for (int rr = 0; rr < 4; ++rr) {
        int m0 = quad * 4 + rr;          // pixel 0..15
        int ja = j0 + m0;
        out[((b * OC + o0) * HH + i) * WW + ja] = acc0[rr];
        out[((b * OC + o1) * HH + i) * WW + ja] = acc1[rr];
    }
}

extern "C" void kernel_launch(void* const* d_in, const int* in_sizes, int n_in,
                              void* d_out, int out_size, void* d_ws, size_t ws_size,
                              hipStream_t stream)
{
    const float* x  = (const float*)d_in[0];
    const float* cw = (const float*)d_in[1];
    const float* pw = (const float*)d_in[2];
    const float* pb = (const float*)d_in[3];
    const float* aw = (const float*)d_in[4];
    const float* ab = (const float*)d_in[5];
    float* out = (float*)d_out;

    char* ws = (char*)d_ws;
    float*  offp = (float*)ws;                        // 2*4*18*9216 = 663552 fp32
    float*  adp  = offp + BB * 4 * 18 * HWX;          // 2*4*3*9216  = 221184 fp32
    float*  wrep = adp + BB * 4 * 3 * HWX;            // 27648 fp32
    __bf16* wbf  = (__bf16*)(wrep + KTOT * 24);       // 147456 bf16 (16B-aligned)
    float*  xT   = (float*)(wbf + (size_t)KTOT * OC); // 2359296 fp32 (16B-aligned)
    // total ws use: ~13.4 MB

    wrep_kernel<<<(KTOT * 24 + 255) / 256, 256, 0, stream>>>(pw, aw, wrep);
    wbf_kernel<<<(KTOT * OC + 255) / 256, 256, 0, stream>>>(cw, wbf);
    xt_kernel<<<BB * HH, 256, 0, stream>>>(x, xT);
    offsets_kernel<<<BB * 144 * 4, 512, 0, stream>>>(x, wrep, offp, adp);
    deform_kernel<<<NWG, 256, 0, stream>>>(xT, offp, adp, pb, ab, wbf, out);
}

// Round 4
// 144.878 us; speedup vs baseline: 1.4911x; 1.3470x over previous
//
#include <hip/hip_runtime.h>
#include <hip/hip_bf16.h>
#include <math.h>

#define BB 2
#define CC 128
#define HH 96
#define WW 96
#define HWX (HH*WW)        // 9216
#define KTOT (CC*9)        // 1152
#define OC 128
#define KHALF 576          // deform K split: 64 channels per half
#define ROWH 600           // 576 + 24 pad; 1200 B row stride (16B-aligned for b128 reads)
#define QC 32              // offsets: channels per block
#define PXB 16             // pixels per deform block
#define NWG (BB*HWX/PXB)   // 1152 deform blocks

typedef __attribute__((ext_vector_type(8))) __bf16 bf16x8;
typedef __attribute__((ext_vector_type(4))) __bf16 bf16x4;
typedef __attribute__((ext_vector_type(4))) float floatx4;

// ---------------- K0a: repack pconv_w/adconv_w -> wrep[(c*9+tap)*24 + o] --------------
__global__ __launch_bounds__(256) void wrep_kernel(const float* __restrict__ pw,
                                                   const float* __restrict__ aw,
                                                   float* __restrict__ wrep)
{
    int t = blockIdx.x * 256 + threadIdx.x;    // 0..27647
    if (t >= KTOT * 24) return;
    int tapch = t / 24;
    int o = t - tapch * 24;
    float v = 0.f;
    if (o < 18)      v = pw[o * KTOT + tapch];
    else if (o < 21) v = aw[(o - 18) * KTOT + tapch];
    wrep[t] = v;
}

// ---------------- K0b: conv_w fp32 -> bf16 in MFMA-fragment-linear layout -------------
// Fragment (wv,h,kt,f): 64 lanes x 8 bf16. Element t decomposes as
//   t = ((((wv*2+h)*18 + kt)*2 + f)*64 + lane)*8 + e,  lane = quad*16 + l15.
// Content: row o = wv*32 + f*16 + l15, k' = h*576 + kt*32 + quad*8 + e,
// original k = (h*64 + (r&63))*9 + (r>>6) with r = k' - h*576.  Fragment contents are
// bit-identical to the previous [o][k'] layout, so the GEMM is unchanged.
__global__ __launch_bounds__(256) void wbf_kernel(const float* __restrict__ w,
                                                  __bf16* __restrict__ wbf)
{
    int t = blockIdx.x * 256 + threadIdx.x;
    if (t >= KTOT * OC) return;
    int e    = t & 7;
    int lane = (t >> 3) & 63;
    int f    = (t >> 9) & 1;
    int rest = t >> 10;          // (wv*2+h)*18 + kt, 0..143
    int kt   = rest % 18;
    int wh   = rest / 18;        // wv*2+h
    int h    = wh & 1;
    int wv   = wh >> 1;
    int quad = lane >> 4, l15 = lane & 15;
    int o  = wv * 32 + f * 16 + l15;
    int r  = kt * 32 + quad * 8 + e;     // k' within half, 0..575
    int n  = r >> 6;
    int cl = r & 63;
    int c  = h * 64 + cl;
    wbf[t] = (__bf16)w[(size_t)o * KTOT + c * 9 + n];
}

// ---------------- K0c: x NCHW -> NHWC (xT[((b*96+i)*96+j)*128 + c]) -------------------
__global__ __launch_bounds__(256) void xt_kernel(const float* __restrict__ x,
                                                 float* __restrict__ xT)
{
    __shared__ float tile[96 * 129];   // [j][c], +1 col pad -> conflict-free both phases
    int blk = blockIdx.x;              // b*96 + i
    int b = blk / HH, i = blk % HH;
    int tid = threadIdx.x;
    const float* src = x + (size_t)b * CC * HWX + (size_t)i * WW;
    for (int idx = tid; idx < CC * WW; idx += 256) {
        int c = idx / WW, j = idx - c * WW;
        tile[j * 129 + c] = src[(size_t)c * HWX + j];
    }
    __syncthreads();
    float* dst = xT + ((size_t)b * HWX + (size_t)i * WW) * CC;
    for (int idx = tid; idx < CC * WW; idx += 256) {
        int j = idx >> 7, c = idx & 127;
        dst[idx] = tile[j * 129 + c];
    }
}

// ---------------- K1: offsets conv, c-quarter blocks, partial-sum outputs -------------
// grid = BB*144*4, 512 thr. Writes per-quarter partials (no atomics, no zero pass);
// deform's metadata phase sums the 4 partials.
__global__ __launch_bounds__(512) void offsets_kernel(
    const float* __restrict__ x, const float* __restrict__ wrep,
    float* __restrict__ offp, float* __restrict__ adp)
{
    __shared__ float sm[10112];   // [0,3200): xs[32][10][10]; [3200,10112): wl[32*9*24];
                                  // reduce phase aliases [0,9408)
    int blk = blockIdx.x;
    int cq = blk & 3;
    int rest = blk >> 2;
    int b = rest / 144;
    int t2 = rest % 144;
    int ti = t2 / 12, tj = t2 % 12;
    int i0 = ti * 8, j0 = tj * 8;
    int tid = threadIdx.x;
    float* xs = sm;
    float* wl = sm + 3200;

    for (int idx = tid; idx < 3200; idx += 512) {
        int cl = idx / 100; int r = idx % 100; int u = r / 10, v = r % 10;
        int gi = i0 + u - 1, gj = j0 + v - 1;
        float val = 0.f;
        if (gi >= 0 && gi < HH && gj >= 0 && gj < WW)
            val = x[((b * CC + cq * QC + cl) * HH + gi) * WW + gj];
        xs[idx] = val;
    }
    {   // weights: 32*9*24 = 6912 floats, coalesced float4
        const float4* src = (const float4*)(wrep + (size_t)(cq * QC) * 9 * 24);
        float4* dst = (float4*)wl;
        for (int idx = tid; idx < 1728; idx += 512) dst[idx] = src[idx];
    }
    __syncthreads();

    int wave = tid >> 6, lane = tid & 63;
    int pi = lane >> 3, pj = lane & 7;
    float acc[21];
#pragma unroll
    for (int o = 0; o < 21; ++o) acc[o] = 0.f;

    for (int cc = 0; cc < 4; ++cc) {
        int cl = wave * 4 + cc;
        const float* xr = &xs[cl * 100 + pi * 10 + pj];
        const float* wr = &wl[cl * 9 * 24];
#pragma unroll
        for (int di = 0; di < 3; ++di) {
#pragma unroll
            for (int dj = 0; dj < 3; ++dj) {
                int tap = di * 3 + dj;
                float xv = xr[di * 10 + dj];
                const float4* wp = (const float4*)(wr + tap * 24);
                float4 w0 = wp[0], w1 = wp[1], w2 = wp[2], w3 = wp[3], w4 = wp[4];
                float w20 = wr[tap * 24 + 20];
                acc[0]  += xv * w0.x; acc[1]  += xv * w0.y; acc[2]  += xv * w0.z; acc[3]  += xv * w0.w;
                acc[4]  += xv * w1.x; acc[5]  += xv * w1.y; acc[6]  += xv * w1.z; acc[7]  += xv * w1.w;
                acc[8]  += xv * w2.x; acc[9]  += xv * w2.y; acc[10] += xv * w2.z; acc[11] += xv * w2.w;
                acc[12] += xv * w3.x; acc[13] += xv * w3.y; acc[14] += xv * w3.z; acc[15] += xv * w3.w;
                acc[16] += xv * w4.x; acc[17] += xv * w4.y; acc[18] += xv * w4.z; acc[19] += xv * w4.w;
                acc[20] += xv * w20;
            }
        }
    }
    __syncthreads();                 // xs/wl dead; alias reduce buffer over sm
    if (wave > 0) {
        float* red = &sm[((wave - 1) * 64 + lane) * 21];
#pragma unroll
        for (int o = 0; o < 21; ++o) red[o] = acc[o];
    }
    __syncthreads();
    if (wave == 0) {
#pragma unroll
        for (int r = 0; r < 7; ++r) {
            const float* red = &sm[(r * 64 + lane) * 21];
#pragma unroll
            for (int o = 0; o < 21; ++o) acc[o] += red[o];
        }
        int i = i0 + pi, j = j0 + pj;
        int ij = i * WW + j;
        float* op = offp + (size_t)((b * 4 + cq) * 18) * HWX + ij;
#pragma unroll
        for (int o = 0; o < 18; ++o) op[(size_t)o * HWX] = acc[o];
        float* ap = adp + (size_t)((b * 4 + cq) * 3) * HWX + ij;
#pragma unroll
        for (int o = 0; o < 3; ++o) ap[(size_t)o * HWX] = acc[18 + o];
    }
}

// ---------------- K2: sampling (NHWC float4 gathers) + MFMA GEMM ----------------------
// grid = 1152 blocks, 256 thr, XCD-swizzled (each XCD owns a 24-row slab -> L2-local).
// Quad-coalesced lane maps:
//   gather: gpx = tid>>4, gs = tid&15 -> lanes 0..3 read 4 consecutive 16B chunks of
//           ONE pixel's channel block = one 64B line per quad (4x fewer TA requests).
//   B-operand: fragment-linear wbf -> wave-uniform base + lane*16B = 1024B/instr.
__global__ __launch_bounds__(256, 4) void deform_kernel(
    const float* __restrict__ xT, const float* __restrict__ offp,
    const float* __restrict__ adp, const float* __restrict__ pb,
    const float* __restrict__ ab, const __bf16* __restrict__ wbf,
    float* __restrict__ out)
{
    __shared__ __align__(16) __bf16 xoff[PXB * ROWH];   // 19200 B
    __shared__ int4   qidx[PXB * 9];                    // flat plane offsets (lt,rb,lb,rt)
    __shared__ float4 gwt[PXB * 9];                     // weights, zeroed when OOB

    int tid = threadIdx.x;
    // XCD-aware swizzle: contiguous slab per XCD (NWG % 8 == 0 -> bijective)
    int lb = (blockIdx.x & 7) * (NWG >> 3) + (blockIdx.x >> 3);
    int gid0 = lb * PXB;
    int b  = gid0 / HWX;
    int r0 = gid0 - b * HWX;
    int i  = r0 / WW;
    int j0 = r0 % WW;

    if (tid < PXB * 9) {
        int t = tid;
        int px = t / 9, n = t % 9;
        int j = j0 + px;
        int ij = i * WW + j;
        float offx = pb[n], offy = pb[9 + n], zad = ab[n % 3];
#pragma unroll
        for (int cq = 0; cq < 4; ++cq) {
            const float* op = offp + (size_t)((b * 4 + cq) * 18) * HWX + ij;
            offx += op[(size_t)n * HWX];
            offy += op[(size_t)(9 + n) * HWX];
            zad  += adp[(size_t)((b * 4 + cq) * 3 + (n % 3)) * HWX + ij];
        }
        float ad   = 2.f * (1.f - 1.f / (1.f + expf(-zad)));
        float pnx = (float)(n / 3 - 1), pny = (float)(n % 3 - 1);
        float pxf = (float)(i + 1) + pnx * (1.f + ad) + offx;
        float pyf = (float)(j + 1) + pny * (1.f + ad) + offy;
        float flx = floorf(pxf), fly = floorf(pyf);
        float qltx = fminf(fmaxf(flx, 0.f), 97.f);
        float qlty = fminf(fmaxf(fly, 0.f), 97.f);
        float qrbx = fminf(fmaxf(flx + 1.f, 0.f), 97.f);
        float qrby = fminf(fmaxf(fly + 1.f, 0.f), 97.f);
        bool mx = (pxf < 1.f) || (pxf > 96.f);
        bool my = (pyf < 1.f) || (pyf > 96.f);
        float pxm = mx ? flx : pxf; pxm = fminf(fmaxf(pxm, 0.f), 97.f);
        float pym = my ? fly : pyf; pym = fminf(fmaxf(pym, 0.f), 97.f);
        float glt = (1.f + (qltx - pxm)) * (1.f + (qlty - pym));
        float grb = (1.f - (qrbx - pxm)) * (1.f - (qrby - pym));
        float glb = (1.f + (qltx - pxm)) * (1.f - (qrby - pym));
        float grt = (1.f - (qrbx - pxm)) * (1.f + (qlty - pym));
        int ilt = (int)qltx, jlt = (int)qlty, irb = (int)qrbx, jrb = (int)qrby;
        bool m_lt = (ilt >= 1) & (ilt <= 96) & (jlt >= 1) & (jlt <= 96);
        bool m_rb = (irb >= 1) & (irb <= 96) & (jrb >= 1) & (jrb <= 96);
        bool m_lb = (ilt >= 1) & (ilt <= 96) & (jrb >= 1) & (jrb <= 96);
        bool m_rt = (irb >= 1) & (irb <= 96) & (jlt >= 1) & (jlt <= 96);
        // folded OOB: weight 0 + safe index 0 == (in-bounds ? x : 0) contribution
        qidx[t] = make_int4(m_lt ? (ilt - 1) * WW + (jlt - 1) : 0,
                            m_rb ? (irb - 1) * WW + (jrb - 1) : 0,
                            m_lb ? (ilt - 1) * WW + (jrb - 1) : 0,
                            m_rt ? (irb - 1) * WW + (jlt - 1) : 0);
        gwt[t]  = make_float4(m_lt ? glt : 0.f, m_rb ? grb : 0.f,
                              m_lb ? glb : 0.f, m_rt ? grt : 0.f);
    }
    __syncthreads();

    int wv = tid >> 6, lane = tid & 63;
    int quad = lane >> 4, l15 = lane & 15;
    int o0 = wv * 32 + l15;
    int o1 = o0 + 16;
    floatx4 acc0 = {0,0,0,0}, acc1 = {0,0,0,0};
    const __bf16* arow = &xoff[l15 * ROWH];
    const __bf16* wlan = wbf + (size_t)lane * 8;   // fragment-linear B base

    int gpx = tid >> 4;                 // gather pixel (quad-coalesced map)
    int gs  = tid & 15;                 // 4-channel group
    __bf16* grow = &xoff[gpx * ROWH];
    const int4*   qrow = &qidx[gpx * 9];
    const float4* grw  = &gwt[gpx * 9];
    const float* xb = xT + (size_t)b * HWX * CC + gs * 4;

    for (int h = 0; h < 2; ++h) {
        const float* xh = xb + h * 64;
#pragma unroll
        for (int n = 0; n < 9; ++n) {
            int4 q = qrow[n];
            float4 g = grw[n];
            float4 vlt = *(const float4*)(xh + (size_t)q.x * CC);
            float4 vrb = *(const float4*)(xh + (size_t)q.y * CC);
            float4 vlb = *(const float4*)(xh + (size_t)q.z * CC);
            float4 vrt = *(const float4*)(xh + (size_t)q.w * CC);
            bf16x4 o;   // same per-channel expression as verified kernel: lt,rb,lb,rt
            o[0] = (__bf16)(g.x * vlt.x + g.y * vrb.x + g.z * vlb.x + g.w * vrt.x);
            o[1] = (__bf16)(g.x * vlt.y + g.y * vrb.y + g.z * vlb.y + g.w * vrt.y);
            o[2] = (__bf16)(g.x * vlt.z + g.y * vrb.z + g.z * vlb.z + g.w * vrt.z);
            o[3] = (__bf16)(g.x * vlt.w + g.y * vrb.w + g.z * vlb.w + g.w * vrt.w);
            *(bf16x4*)(grow + n * 64 + gs * 4) = o;   // k' = tap*64 + cl, 8B store
        }
        __syncthreads();

        const __bf16* wb = wlan + (size_t)((wv * 2 + h) * 18) * 1024;
        for (int kt = 0; kt < 18; ++kt) {
            int kl = kt * 32 + quad * 8;
            bf16x8 a0 = *(const bf16x8*)(arow + kl);
            bf16x8 b0 = *(const bf16x8*)(wb + kt * 1024);
            bf16x8 b1 = *(const bf16x8*)(wb + kt * 1024 + 512);
            acc0 = __builtin_amdgcn_mfma_f32_16x16x32_bf16(a0, b0, acc0, 0, 0, 0);
            acc1 = __builtin_amdgcn_mfma_f32_16x16x32_bf16(a0, b1, acc1, 0, 0, 0);
        }
        __syncthreads();
    }

#pragma unroll
    for (int rr = 0; rr < 4; ++rr) {
        int m0 = quad * 4 + rr;          // pixel 0..15
        int ja = j0 + m0;
        out[((b * OC + o0) * HH + i) * WW + ja] = acc0[rr];
        out[((b * OC + o1) * HH + i) * WW + ja] = acc1[rr];
    }
}

extern "C" void kernel_launch(void* const* d_in, const int* in_sizes, int n_in,
                              void* d_out, int out_size, void* d_ws, size_t ws_size,
                              hipStream_t stream)
{
    const float* x  = (const float*)d_in[0];
    const float* cw = (const float*)d_in[1];
    const float* pw = (const float*)d_in[2];
    const float* pb = (const float*)d_in[3];
    const float* aw = (const float*)d_in[4];
    const float* ab = (const float*)d_in[5];
    float* out = (float*)d_out;

    char* ws = (char*)d_ws;
    float*  offp = (float*)ws;                        // 2*4*18*9216 = 663552 fp32
    float*  adp  = offp + BB * 4 * 18 * HWX;          // 2*4*3*9216  = 221184 fp32
    float*  wrep = adp + BB * 4 * 3 * HWX;            // 27648 fp32
    __bf16* wbf  = (__bf16*)(wrep + KTOT * 24);       // 147456 bf16 (16B-aligned)
    float*  xT   = (float*)(wbf + (size_t)KTOT * OC); // 2359296 fp32 (16B-aligned)
    // total ws use: ~13.4 MB

    wrep_kernel<<<(KTOT * 24 + 255) / 256, 256, 0, stream>>>(pw, aw, wrep);
    wbf_kernel<<<(KTOT * OC + 255) / 256, 256, 0, stream>>>(cw, wbf);
    xt_kernel<<<BB * HH, 256, 0, stream>>>(x, xT);
    offsets_kernel<<<BB * 144 * 4, 512, 0, stream>>>(x, wrep, offp, adp);
    deform_kernel<<<NWG, 256, 0, stream>>>(xT, offp, adp, pb, ab, wbf, out);
}

// Round 5
// 137.099 us; speedup vs baseline: 1.5757x; 1.0567x over previous
//
#include <hip/hip_runtime.h>
#include <hip/hip_bf16.h>
#include <math.h>

#define BB 2
#define CC 128
#define HH 96
#define WW 96
#define HWX (HH*WW)        // 9216
#define KTOT (CC*9)        // 1152
#define OC 128
#define KHALF 576          // deform K split: 64 channels per half
#define ROWH 600           // 576 + 24 pad; 1200 B row stride (16B-aligned for b128 reads)
#define QC 32              // offsets: channels per block
#define PXB 16             // pixels per deform block
#define NWG (BB*HWX/PXB)   // 1152 deform blocks

typedef __attribute__((ext_vector_type(8))) __bf16 bf16x8;
typedef __attribute__((ext_vector_type(4))) __bf16 bf16x4;
typedef __attribute__((ext_vector_type(4))) float floatx4;

// ---------------- K0a: repack pconv_w/adconv_w -> wrep[(c*9+tap)*24 + o] --------------
__global__ __launch_bounds__(256) void wrep_kernel(const float* __restrict__ pw,
                                                   const float* __restrict__ aw,
                                                   float* __restrict__ wrep)
{
    int t = blockIdx.x * 256 + threadIdx.x;    // 0..27647
    if (t >= KTOT * 24) return;
    int tapch = t / 24;
    int o = t - tapch * 24;
    float v = 0.f;
    if (o < 18)      v = pw[o * KTOT + tapch];
    else if (o < 21) v = aw[(o - 18) * KTOT + tapch];
    wrep[t] = v;
}

// ---------------- K0b: conv_w fp32 -> bf16 in MFMA-fragment-linear layout -------------
// Fragment (wv,h,kt,f): 64 lanes x 8 bf16. Element t decomposes as
//   t = ((((wv*2+h)*18 + kt)*2 + f)*64 + lane)*8 + e,  lane = quad*16 + l15.
// Content: row o = wv*32 + f*16 + l15, k' = h*576 + kt*32 + quad*8 + e,
// original k = (h*64 + (r&63))*9 + (r>>6) with r = k' - h*576.  Fragment contents are
// bit-identical to the previous [o][k'] layout, so the GEMM is unchanged.
__global__ __launch_bounds__(256) void wbf_kernel(const float* __restrict__ w,
                                                  __bf16* __restrict__ wbf)
{
    int t = blockIdx.x * 256 + threadIdx.x;
    if (t >= KTOT * OC) return;
    int e    = t & 7;
    int lane = (t >> 3) & 63;
    int f    = (t >> 9) & 1;
    int rest = t >> 10;          // (wv*2+h)*18 + kt, 0..143
    int kt   = rest % 18;
    int wh   = rest / 18;        // wv*2+h
    int h    = wh & 1;
    int wv   = wh >> 1;
    int quad = lane >> 4, l15 = lane & 15;
    int o  = wv * 32 + f * 16 + l15;
    int r  = kt * 32 + quad * 8 + e;     // k' within half, 0..575
    int n  = r >> 6;
    int cl = r & 63;
    int c  = h * 64 + cl;
    wbf[t] = (__bf16)w[(size_t)o * KTOT + c * 9 + n];
}

// ---------------- K0c: x NCHW -> NHWC (xT[((b*96+i)*96+j)*128 + c]) -------------------
__global__ __launch_bounds__(256) void xt_kernel(const float* __restrict__ x,
                                                 float* __restrict__ xT)
{
    __shared__ float tile[96 * 129];   // [j][c], +1 col pad -> conflict-free both phases
    int blk = blockIdx.x;              // b*96 + i
    int b = blk / HH, i = blk % HH;
    int tid = threadIdx.x;
    const float* src = x + (size_t)b * CC * HWX + (size_t)i * WW;
    for (int idx = tid; idx < CC * WW; idx += 256) {
        int c = idx / WW, j = idx - c * WW;
        tile[j * 129 + c] = src[(size_t)c * HWX + j];
    }
    __syncthreads();
    float* dst = xT + ((size_t)b * HWX + (size_t)i * WW) * CC;
    for (int idx = tid; idx < CC * WW; idx += 256) {
        int j = idx >> 7, c = idx & 127;
        dst[idx] = tile[j * 129 + c];
    }
}

// ---------------- K1: offsets conv, scalar-pipe weights, partial-sum outputs ----------
// grid = BB*144*4, 512 thr. Weights are wave-uniform per (cc,tap): readfirstlane the
// base index -> s_load_dwordx* on the SMEM pipe (scalar K$), so the LDS pipe carries
// only the per-lane x reads (1 ds_read_b32 per 21 FMAs instead of 7 ds_reads).
// FMA order per output unchanged -> bit-identical results.
__global__ __launch_bounds__(512) void offsets_kernel(
    const float* __restrict__ x, const float* __restrict__ wrep,
    float* __restrict__ offp, float* __restrict__ adp)
{
    __shared__ float sm[9408];    // [0,3200): xs[32][10][10]; reduce aliases [0,9408)
    int blk = blockIdx.x;
    int cq = blk & 3;
    int rest = blk >> 2;
    int b = rest / 144;
    int t2 = rest % 144;
    int ti = t2 / 12, tj = t2 % 12;
    int i0 = ti * 8, j0 = tj * 8;
    int tid = threadIdx.x;
    float* xs = sm;

    for (int idx = tid; idx < 3200; idx += 512) {
        int cl = idx / 100; int r = idx % 100; int u = r / 10, v = r % 10;
        int gi = i0 + u - 1, gj = j0 + v - 1;
        float val = 0.f;
        if (gi >= 0 && gi < HH && gj >= 0 && gj < WW)
            val = x[((b * CC + cq * QC + cl) * HH + gi) * WW + gj];
        xs[idx] = val;
    }
    __syncthreads();

    int wave = tid >> 6, lane = tid & 63;
    int pi = lane >> 3, pj = lane & 7;
    float acc[21];
#pragma unroll
    for (int o = 0; o < 21; ++o) acc[o] = 0.f;

    const float* wq = wrep + (size_t)(cq * QC) * 216;   // this quarter's weights

    for (int cc = 0; cc < 4; ++cc) {
        int cl = wave * 4 + cc;
        const float* xr = &xs[cl * 100 + pi * 10 + pj];
        int cb = __builtin_amdgcn_readfirstlane(cl * 216);   // SGPR base -> s_load path
        const float* wc = wq + cb;
#pragma unroll
        for (int tap = 0; tap < 9; ++tap) {
            int di = tap / 3, dj = tap % 3;
            float xv = xr[di * 10 + dj];
            const float* wr = wc + tap * 24;   // imm offsets 0..848B: scalar loads
            acc[0]  += xv * wr[0];  acc[1]  += xv * wr[1];  acc[2]  += xv * wr[2];
            acc[3]  += xv * wr[3];  acc[4]  += xv * wr[4];  acc[5]  += xv * wr[5];
            acc[6]  += xv * wr[6];  acc[7]  += xv * wr[7];  acc[8]  += xv * wr[8];
            acc[9]  += xv * wr[9];  acc[10] += xv * wr[10]; acc[11] += xv * wr[11];
            acc[12] += xv * wr[12]; acc[13] += xv * wr[13]; acc[14] += xv * wr[14];
            acc[15] += xv * wr[15]; acc[16] += xv * wr[16]; acc[17] += xv * wr[17];
            acc[18] += xv * wr[18]; acc[19] += xv * wr[19]; acc[20] += xv * wr[20];
        }
    }
    __syncthreads();                 // xs dead; alias reduce buffer over sm
    if (wave > 0) {
        float* red = &sm[((wave - 1) * 64 + lane) * 21];
#pragma unroll
        for (int o = 0; o < 21; ++o) red[o] = acc[o];
    }
    __syncthreads();
    if (wave == 0) {
#pragma unroll
        for (int r = 0; r < 7; ++r) {
            const float* red = &sm[(r * 64 + lane) * 21];
#pragma unroll
            for (int o = 0; o < 21; ++o) acc[o] += red[o];
        }
        int i = i0 + pi, j = j0 + pj;
        int ij = i * WW + j;
        float* op = offp + (size_t)((b * 4 + cq) * 18) * HWX + ij;
#pragma unroll
        for (int o = 0; o < 18; ++o) op[(size_t)o * HWX] = acc[o];
        float* ap = adp + (size_t)((b * 4 + cq) * 3) * HWX + ij;
#pragma unroll
        for (int o = 0; o < 3; ++o) ap[(size_t)o * HWX] = acc[18 + o];
    }
}

// ---------------- K2: sampling (NHWC float4 gathers) + MFMA GEMM ----------------------
// grid = 1152 blocks, 256 thr, XCD-swizzled (each XCD owns a 24-row slab -> L2-local).
// Quad-coalesced lane maps:
//   gather: gpx = tid>>4, gs = tid&15 -> lanes 0..3 read 4 consecutive 16B chunks of
//           ONE pixel's channel block = one 64B line per quad (4x fewer TA requests).
//   B-operand: fragment-linear wbf -> wave-uniform base + lane*16B = 1024B/instr.
__global__ __launch_bounds__(256, 4) void deform_kernel(
    const float* __restrict__ xT, const float* __restrict__ offp,
    const float* __restrict__ adp, const float* __restrict__ pb,
    const float* __restrict__ ab, const __bf16* __restrict__ wbf,
    float* __restrict__ out)
{
    __shared__ __align__(16) __bf16 xoff[PXB * ROWH];   // 19200 B
    __shared__ int4   qidx[PXB * 9];                    // flat plane offsets (lt,rb,lb,rt)
    __shared__ float4 gwt[PXB * 9];                     // weights, zeroed when OOB

    int tid = threadIdx.x;
    // XCD-aware swizzle: contiguous slab per XCD (NWG % 8 == 0 -> bijective)
    int lb = (blockIdx.x & 7) * (NWG >> 3) + (blockIdx.x >> 3);
    int gid0 = lb * PXB;
    int b  = gid0 / HWX;
    int r0 = gid0 - b * HWX;
    int i  = r0 / WW;
    int j0 = r0 % WW;

    if (tid < PXB * 9) {
        int t = tid;
        int px = t / 9, n = t % 9;
        int j = j0 + px;
        int ij = i * WW + j;
        float offx = pb[n], offy = pb[9 + n], zad = ab[n % 3];
#pragma unroll
        for (int cq = 0; cq < 4; ++cq) {
            const float* op = offp + (size_t)((b * 4 + cq) * 18) * HWX + ij;
            offx += op[(size_t)n * HWX];
            offy += op[(size_t)(9 + n) * HWX];
            zad  += adp[(size_t)((b * 4 + cq) * 3 + (n % 3)) * HWX + ij];
        }
        float ad   = 2.f * (1.f - 1.f / (1.f + expf(-zad)));
        float pnx = (float)(n / 3 - 1), pny = (float)(n % 3 - 1);
        float pxf = (float)(i + 1) + pnx * (1.f + ad) + offx;
        float pyf = (float)(j + 1) + pny * (1.f + ad) + offy;
        float flx = floorf(pxf), fly = floorf(pyf);
        float qltx = fminf(fmaxf(flx, 0.f), 97.f);
        float qlty = fminf(fmaxf(fly, 0.f), 97.f);
        float qrbx = fminf(fmaxf(flx + 1.f, 0.f), 97.f);
        float qrby = fminf(fmaxf(fly + 1.f, 0.f), 97.f);
        bool mx = (pxf < 1.f) || (pxf > 96.f);
        bool my = (pyf < 1.f) || (pyf > 96.f);
        float pxm = mx ? flx : pxf; pxm = fminf(fmaxf(pxm, 0.f), 97.f);
        float pym = my ? fly : pyf; pym = fminf(fmaxf(pym, 0.f), 97.f);
        float glt = (1.f + (qltx - pxm)) * (1.f + (qlty - pym));
        float grb = (1.f - (qrbx - pxm)) * (1.f - (qrby - pym));
        float glb = (1.f + (qltx - pxm)) * (1.f - (qrby - pym));
        float grt = (1.f - (qrbx - pxm)) * (1.f + (qlty - pym));
        int ilt = (int)qltx, jlt = (int)qlty, irb = (int)qrbx, jrb = (int)qrby;
        bool m_lt = (ilt >= 1) & (ilt <= 96) & (jlt >= 1) & (jlt <= 96);
        bool m_rb = (irb >= 1) & (irb <= 96) & (jrb >= 1) & (jrb <= 96);
        bool m_lb = (ilt >= 1) & (ilt <= 96) & (jrb >= 1) & (jrb <= 96);
        bool m_rt = (irb >= 1) & (irb <= 96) & (jlt >= 1) & (jlt <= 96);
        // folded OOB: weight 0 + safe index 0 == (in-bounds ? x : 0) contribution
        qidx[t] = make_int4(m_lt ? (ilt - 1) * WW + (jlt - 1) : 0,
                            m_rb ? (irb - 1) * WW + (jrb - 1) : 0,
                            m_lb ? (ilt - 1) * WW + (jrb - 1) : 0,
                            m_rt ? (irb - 1) * WW + (jlt - 1) : 0);
        gwt[t]  = make_float4(m_lt ? glt : 0.f, m_rb ? grb : 0.f,
                              m_lb ? glb : 0.f, m_rt ? grt : 0.f);
    }
    __syncthreads();

    int wv = tid >> 6, lane = tid & 63;
    int quad = lane >> 4, l15 = lane & 15;
    int o0 = wv * 32 + l15;
    int o1 = o0 + 16;
    floatx4 acc0 = {0,0,0,0}, acc1 = {0,0,0,0};
    const __bf16* arow = &xoff[l15 * ROWH];
    const __bf16* wlan = wbf + (size_t)lane * 8;   // fragment-linear B base

    int gpx = tid >> 4;                 // gather pixel (quad-coalesced map)
    int gs  = tid & 15;                 // 4-channel group
    __bf16* grow = &xoff[gpx * ROWH];
    const int4*   qrow = &qidx[gpx * 9];
    const float4* grw  = &gwt[gpx * 9];
    const float* xb = xT + (size_t)b * HWX * CC + gs * 4;

    for (int h = 0; h < 2; ++h) {
        const float* xh = xb + h * 64;
#pragma unroll
        for (int n = 0; n < 9; ++n) {
            int4 q = qrow[n];
            float4 g = grw[n];
            float4 vlt = *(const float4*)(xh + (size_t)q.x * CC);
            float4 vrb = *(const float4*)(xh + (size_t)q.y * CC);
            float4 vlb = *(const float4*)(xh + (size_t)q.z * CC);
            float4 vrt = *(const float4*)(xh + (size_t)q.w * CC);
            bf16x4 o;   // same per-channel expression as verified kernel: lt,rb,lb,rt
            o[0] = (__bf16)(g.x * vlt.x + g.y * vrb.x + g.z * vlb.x + g.w * vrt.x);
            o[1] = (__bf16)(g.x * vlt.y + g.y * vrb.y + g.z * vlb.y + g.w * vrt.y);
            o[2] = (__bf16)(g.x * vlt.z + g.y * vrb.z + g.z * vlb.z + g.w * vrt.z);
            o[3] = (__bf16)(g.x * vlt.w + g.y * vrb.w + g.z * vlb.w + g.w * vrt.w);
            *(bf16x4*)(grow + n * 64 + gs * 4) = o;   // k' = tap*64 + cl, 8B store
        }
        __syncthreads();

        const __bf16* wb = wlan + (size_t)((wv * 2 + h) * 18) * 1024;
        for (int kt = 0; kt < 18; ++kt) {
            int kl = kt * 32 + quad * 8;
            bf16x8 a0 = *(const bf16x8*)(arow + kl);
            bf16x8 b0 = *(const bf16x8*)(wb + kt * 1024);
            bf16x8 b1 = *(const bf16x8*)(wb + kt * 1024 + 512);
            acc0 = __builtin_amdgcn_mfma_f32_16x16x32_bf16(a0, b0, acc0, 0, 0, 0);
            acc1 = __builtin_amdgcn_mfma_f32_16x16x32_bf16(a0, b1, acc1, 0, 0, 0);
        }
        __syncthreads();
    }

#pragma unroll
    for (int rr = 0; rr < 4; ++rr) {
        int m0 = quad * 4 + rr;          // pixel 0..15
        int ja = j0 + m0;
        out[((b * OC + o0) * HH + i) * WW + ja] = acc0[rr];
        out[((b * OC + o1) * HH + i) * WW + ja] = acc1[rr];
    }
}

extern "C" void kernel_launch(void* const* d_in, const int* in_sizes, int n_in,
                              void* d_out, int out_size, void* d_ws, size_t ws_size,
                              hipStream_t stream)
{
    const float* x  = (const float*)d_in[0];
    const float* cw = (const float*)d_in[1];
    const float* pw = (const float*)d_in[2];
    const float* pb = (const float*)d_in[3];
    const float* aw = (const float*)d_in[4];
    const float* ab = (const float*)d_in[5];
    float* out = (float*)d_out;

    char* ws = (char*)d_ws;
    float*  offp = (float*)ws;                        // 2*4*18*9216 = 663552 fp32
    float*  adp  = offp + BB * 4 * 18 * HWX;          // 2*4*3*9216  = 221184 fp32
    float*  wrep = adp + BB * 4 * 3 * HWX;            // 27648 fp32
    __bf16* wbf  = (__bf16*)(wrep + KTOT * 24);       // 147456 bf16 (16B-aligned)
    float*  xT   = (float*)(wbf + (size_t)KTOT * OC); // 2359296 fp32 (16B-aligned)
    // total ws use: ~13.4 MB

    wrep_kernel<<<(KTOT * 24 + 255) / 256, 256, 0, stream>>>(pw, aw, wrep);
    wbf_kernel<<<(KTOT * OC + 255) / 256, 256, 0, stream>>>(cw, wbf);
    xt_kernel<<<BB * HH, 256, 0, stream>>>(x, xT);
    offsets_kernel<<<BB * 144 * 4, 512, 0, stream>>>(x, wrep, offp, adp);
    deform_kernel<<<NWG, 256, 0, stream>>>(xT, offp, adp, pb, ab, wbf, out);
}

// Round 6
// 133.092 us; speedup vs baseline: 1.6232x; 1.0301x over previous
//
#include <hip/hip_runtime.h>
#include <hip/hip_bf16.h>
#include <math.h>

#define BB 2
#define CC 128
#define HH 96
#define WW 96
#define HWX (HH*WW)        // 9216
#define KTOT (CC*9)        // 1152
#define OC 128
#define KHALF 576          // deform K split: 64 channels per half
#define ROWF 1176          // 1152 + 24 pad; 2352 B row stride (16B-aligned, 12 mod 32 banks)
#define QC 32              // offsets: channels per block
#define PXB 16             // pixels per deform block
#define NWG (BB*HWX/PXB)   // 1152 deform blocks

typedef __attribute__((ext_vector_type(8))) __bf16 bf16x8;
typedef __attribute__((ext_vector_type(4))) __bf16 bf16x4;
typedef __attribute__((ext_vector_type(4))) float floatx4;

// ---------------- K0: fused prep (wrep | wbf | xT), branch per block range -----------
// blocks [0,108): wrep; [108,684): wbf; [684,876): x NCHW->NHWC transpose.
__global__ __launch_bounds__(256) void prep_kernel(const float* __restrict__ pw,
                                                   const float* __restrict__ aw,
                                                   const float* __restrict__ cw,
                                                   const float* __restrict__ x,
                                                   float* __restrict__ wrep,
                                                   __bf16* __restrict__ wbf,
                                                   float* __restrict__ xT)
{
    __shared__ float tile[96 * 129];   // xt branch only; [j][c], +1 pad
    int bid = blockIdx.x;
    int tid = threadIdx.x;

    if (bid < 108) {
        // ---- wrep: pconv_w/adconv_w -> wrep[(c*9+tap)*24 + o] ----
        int t = bid * 256 + tid;    // 0..27647
        if (t < KTOT * 24) {
            int tapch = t / 24;
            int o = t - tapch * 24;
            float v = 0.f;
            if (o < 18)      v = pw[o * KTOT + tapch];
            else if (o < 21) v = aw[(o - 18) * KTOT + tapch];
            wrep[t] = v;
        }
    } else if (bid < 684) {
        // ---- wbf: conv_w fp32 -> bf16, MFMA-fragment-linear layout ----
        // t = ((((wv*2+h)*18 + kt)*2 + f)*64 + lane)*8 + e; contents bit-identical
        // to the [o][k'] layout (k' = h*576 + kt*32 + quad*8 + e).
        int t = (bid - 108) * 256 + tid;
        if (t < KTOT * OC) {
            int e    = t & 7;
            int lane = (t >> 3) & 63;
            int f    = (t >> 9) & 1;
            int rest = t >> 10;          // (wv*2+h)*18 + kt, 0..143
            int kt   = rest % 18;
            int wh   = rest / 18;
            int h    = wh & 1;
            int wv   = wh >> 1;
            int quad = lane >> 4, l15 = lane & 15;
            int o  = wv * 32 + f * 16 + l15;
            int r  = kt * 32 + quad * 8 + e;
            int n  = r >> 6;
            int cl = r & 63;
            int c  = h * 64 + cl;
            wbf[t] = (__bf16)cw[(size_t)o * KTOT + c * 9 + n];
        }
    } else {
        // ---- xt: x NCHW -> NHWC (xT[((b*96+i)*96+j)*128 + c]) ----
        int blk = bid - 684;           // b*96 + i
        int b = blk / HH, i = blk % HH;
        const float* src = x + (size_t)b * CC * HWX + (size_t)i * WW;
        for (int idx = tid; idx < CC * WW; idx += 256) {
            int c = idx / WW, j = idx - c * WW;
            tile[j * 129 + c] = src[(size_t)c * HWX + j];
        }
        __syncthreads();
        float* dst = xT + ((size_t)b * HWX + (size_t)i * WW) * CC;
        for (int idx = tid; idx < CC * WW; idx += 256) {
            int j = idx >> 7, c = idx & 127;
            dst[idx] = tile[j * 129 + c];
        }
    }
}

// ---------------- K1: offsets conv, scalar-pipe weights, partial-sum outputs ----------
// grid = BB*144*4, 512 thr. Weights wave-uniform per (cc,tap) via readfirstlane ->
// s_load path; LDS carries only per-lane x reads. FMA order per output unchanged.
__global__ __launch_bounds__(512) void offsets_kernel(
    const float* __restrict__ x, const float* __restrict__ wrep,
    float* __restrict__ offp, float* __restrict__ adp)
{
    __shared__ float sm[9408];    // [0,3200): xs[32][10][10]; reduce aliases [0,9408)
    int blk = blockIdx.x;
    int cq = blk & 3;
    int rest = blk >> 2;
    int b = rest / 144;
    int t2 = rest % 144;
    int ti = t2 / 12, tj = t2 % 12;
    int i0 = ti * 8, j0 = tj * 8;
    int tid = threadIdx.x;
    float* xs = sm;

    for (int idx = tid; idx < 3200; idx += 512) {
        int cl = idx / 100; int r = idx % 100; int u = r / 10, v = r % 10;
        int gi = i0 + u - 1, gj = j0 + v - 1;
        float val = 0.f;
        if (gi >= 0 && gi < HH && gj >= 0 && gj < WW)
            val = x[((b * CC + cq * QC + cl) * HH + gi) * WW + gj];
        xs[idx] = val;
    }
    __syncthreads();

    int wave = tid >> 6, lane = tid & 63;
    int pi = lane >> 3, pj = lane & 7;
    float acc[21];
#pragma unroll
    for (int o = 0; o < 21; ++o) acc[o] = 0.f;

    const float* wq = wrep + (size_t)(cq * QC) * 216;   // this quarter's weights

    for (int cc = 0; cc < 4; ++cc) {
        int cl = wave * 4 + cc;
        const float* xr = &xs[cl * 100 + pi * 10 + pj];
        int cb = __builtin_amdgcn_readfirstlane(cl * 216);   // SGPR base -> s_load path
        const float* wc = wq + cb;
#pragma unroll
        for (int tap = 0; tap < 9; ++tap) {
            int di = tap / 3, dj = tap % 3;
            float xv = xr[di * 10 + dj];
            const float* wr = wc + tap * 24;   // imm offsets: scalar loads
            acc[0]  += xv * wr[0];  acc[1]  += xv * wr[1];  acc[2]  += xv * wr[2];
            acc[3]  += xv * wr[3];  acc[4]  += xv * wr[4];  acc[5]  += xv * wr[5];
            acc[6]  += xv * wr[6];  acc[7]  += xv * wr[7];  acc[8]  += xv * wr[8];
            acc[9]  += xv * wr[9];  acc[10] += xv * wr[10]; acc[11] += xv * wr[11];
            acc[12] += xv * wr[12]; acc[13] += xv * wr[13]; acc[14] += xv * wr[14];
            acc[15] += xv * wr[15]; acc[16] += xv * wr[16]; acc[17] += xv * wr[17];
            acc[18] += xv * wr[18]; acc[19] += xv * wr[19]; acc[20] += xv * wr[20];
        }
    }
    __syncthreads();                 // xs dead; alias reduce buffer over sm
    if (wave > 0) {
        float* red = &sm[((wave - 1) * 64 + lane) * 21];
#pragma unroll
        for (int o = 0; o < 21; ++o) red[o] = acc[o];
    }
    __syncthreads();
    if (wave == 0) {
#pragma unroll
        for (int r = 0; r < 7; ++r) {
            const float* red = &sm[(r * 64 + lane) * 21];
#pragma unroll
            for (int o = 0; o < 21; ++o) acc[o] += red[o];
        }
        int i = i0 + pi, j = j0 + pj;
        int ij = i * WW + j;
        float* op = offp + (size_t)((b * 4 + cq) * 18) * HWX + ij;
#pragma unroll
        for (int o = 0; o < 18; ++o) op[(size_t)o * HWX] = acc[o];
        float* ap = adp + (size_t)((b * 4 + cq) * 3) * HWX + ij;
#pragma unroll
        for (int o = 0; o < 3; ++o) ap[(size_t)o * HWX] = acc[18 + o];
    }
}

// ---------------- K2: sampling + MFMA GEMM, single-pass gather, deep load ILP ---------
// grid = 1152 blocks, 256 thr, XCD-swizzled. One gather phase covers BOTH K-halves
// (72 independent float4 loads per thread, fully unrolled; launch_bounds(256,3) gives
// the allocator ~168 VGPRs so ~20+ loads stay in flight), then ONE barrier, then a
// 36-step barrier-free MFMA chain. Accumulation order identical to the verified
// 2-phase version (h0 kt0..17 then h1 kt0..17) -> bit-identical results.
__global__ __launch_bounds__(256, 3) void deform_kernel(
    const float* __restrict__ xT, const float* __restrict__ offp,
    const float* __restrict__ adp, const float* __restrict__ pb,
    const float* __restrict__ ab, const __bf16* __restrict__ wbf,
    float* __restrict__ out)
{
    __shared__ __align__(16) __bf16 xoff[PXB * ROWF];   // 37632 B, full K rows
    __shared__ int4   qidx[PXB * 9];                    // flat plane offsets (lt,rb,lb,rt)
    __shared__ float4 gwt[PXB * 9];                     // weights, zeroed when OOB

    int tid = threadIdx.x;
    // XCD-aware swizzle: contiguous slab per XCD (NWG % 8 == 0 -> bijective)
    int lb = (blockIdx.x & 7) * (NWG >> 3) + (blockIdx.x >> 3);
    int gid0 = lb * PXB;
    int b  = gid0 / HWX;
    int r0 = gid0 - b * HWX;
    int i  = r0 / WW;
    int j0 = r0 % WW;

    if (tid < PXB * 9) {
        int t = tid;
        int px = t / 9, n = t % 9;
        int j = j0 + px;
        int ij = i * WW + j;
        float offx = pb[n], offy = pb[9 + n], zad = ab[n % 3];
#pragma unroll
        for (int cq = 0; cq < 4; ++cq) {
            const float* op = offp + (size_t)((b * 4 + cq) * 18) * HWX + ij;
            offx += op[(size_t)n * HWX];
            offy += op[(size_t)(9 + n) * HWX];
            zad  += adp[(size_t)((b * 4 + cq) * 3 + (n % 3)) * HWX + ij];
        }
        float ad   = 2.f * (1.f - 1.f / (1.f + expf(-zad)));
        float pnx = (float)(n / 3 - 1), pny = (float)(n % 3 - 1);
        float pxf = (float)(i + 1) + pnx * (1.f + ad) + offx;
        float pyf = (float)(j + 1) + pny * (1.f + ad) + offy;
        float flx = floorf(pxf), fly = floorf(pyf);
        float qltx = fminf(fmaxf(flx, 0.f), 97.f);
        float qlty = fminf(fmaxf(fly, 0.f), 97.f);
        float qrbx = fminf(fmaxf(flx + 1.f, 0.f), 97.f);
        float qrby = fminf(fmaxf(fly + 1.f, 0.f), 97.f);
        bool mx = (pxf < 1.f) || (pxf > 96.f);
        bool my = (pyf < 1.f) || (pyf > 96.f);
        float pxm = mx ? flx : pxf; pxm = fminf(fmaxf(pxm, 0.f), 97.f);
        float pym = my ? fly : pyf; pym = fminf(fmaxf(pym, 0.f), 97.f);
        float glt = (1.f + (qltx - pxm)) * (1.f + (qlty - pym));
        float grb = (1.f - (qrbx - pxm)) * (1.f - (qrby - pym));
        float glb = (1.f + (qltx - pxm)) * (1.f - (qrby - pym));
        float grt = (1.f - (qrbx - pxm)) * (1.f + (qlty - pym));
        int ilt = (int)qltx, jlt = (int)qlty, irb = (int)qrbx, jrb = (int)qrby;
        bool m_lt = (ilt >= 1) & (ilt <= 96) & (jlt >= 1) & (jlt <= 96);
        bool m_rb = (irb >= 1) & (irb <= 96) & (jrb >= 1) & (jrb <= 96);
        bool m_lb = (ilt >= 1) & (ilt <= 96) & (jrb >= 1) & (jrb <= 96);
        bool m_rt = (irb >= 1) & (irb <= 96) & (jlt >= 1) & (jlt <= 96);
        // folded OOB: weight 0 + safe index 0 == (in-bounds ? x : 0) contribution
        qidx[t] = make_int4(m_lt ? (ilt - 1) * WW + (jlt - 1) : 0,
                            m_rb ? (irb - 1) * WW + (jrb - 1) : 0,
                            m_lb ? (ilt - 1) * WW + (jrb - 1) : 0,
                            m_rt ? (irb - 1) * WW + (jlt - 1) : 0);
        gwt[t]  = make_float4(m_lt ? glt : 0.f, m_rb ? grb : 0.f,
                              m_lb ? glb : 0.f, m_rt ? grt : 0.f);
    }
    __syncthreads();

    int wv = tid >> 6, lane = tid & 63;
    int quad = lane >> 4, l15 = lane & 15;
    int o0 = wv * 32 + l15;
    int o1 = o0 + 16;
    floatx4 acc0 = {0,0,0,0}, acc1 = {0,0,0,0};
    const __bf16* arow = &xoff[l15 * ROWF];
    const __bf16* wlan = wbf + (size_t)lane * 8;   // fragment-linear B base

    // ---- single-pass gather: both halves, 72 independent float4 loads ----
    int gpx = tid >> 4;                 // gather pixel (quad-coalesced map)
    int gs  = tid & 15;                 // 4-channel group
    __bf16* grow = &xoff[gpx * ROWF];
    const int4*   qrow = &qidx[gpx * 9];
    const float4* grw  = &gwt[gpx * 9];
    const float* xb = xT + (size_t)b * HWX * CC + gs * 4;

#pragma unroll
    for (int n = 0; n < 9; ++n) {
        int4 q = qrow[n];
        float4 g = grw[n];
        const float* plt = xb + (size_t)q.x * CC;
        const float* prb = xb + (size_t)q.y * CC;
        const float* plb = xb + (size_t)q.z * CC;
        const float* prt = xb + (size_t)q.w * CC;
        float4 lt0 = *(const float4*)plt,        rb0 = *(const float4*)prb;
        float4 lb0 = *(const float4*)plb,        rt0 = *(const float4*)prt;
        float4 lt1 = *(const float4*)(plt + 64), rb1 = *(const float4*)(prb + 64);
        float4 lb1 = *(const float4*)(plb + 64), rt1 = *(const float4*)(prt + 64);
        bf16x4 o0v, o1v;   // same per-channel expression: lt,rb,lb,rt
        o0v[0] = (__bf16)(g.x * lt0.x + g.y * rb0.x + g.z * lb0.x + g.w * rt0.x);
        o0v[1] = (__bf16)(g.x * lt0.y + g.y * rb0.y + g.z * lb0.y + g.w * rt0.y);
        o0v[2] = (__bf16)(g.x * lt0.z + g.y * rb0.z + g.z * lb0.z + g.w * rt0.z);
        o0v[3] = (__bf16)(g.x * lt0.w + g.y * rb0.w + g.z * lb0.w + g.w * rt0.w);
        o1v[0] = (__bf16)(g.x * lt1.x + g.y * rb1.x + g.z * lb1.x + g.w * rt1.x);
        o1v[1] = (__bf16)(g.x * lt1.y + g.y * rb1.y + g.z * lb1.y + g.w * rt1.y);
        o1v[2] = (__bf16)(g.x * lt1.z + g.y * rb1.z + g.z * lb1.z + g.w * rt1.z);
        o1v[3] = (__bf16)(g.x * lt1.w + g.y * rb1.w + g.z * lb1.w + g.w * rt1.w);
        *(bf16x4*)(grow + n * 64 + gs * 4) = o0v;            // k' = tap*64 + cl (h0)
        *(bf16x4*)(grow + KHALF + n * 64 + gs * 4) = o1v;    // k' = 576 + tap*64 + cl
    }
    __syncthreads();

    // ---- barrier-free 36-step MFMA chain (order identical to 2-phase version) ----
#pragma unroll
    for (int h = 0; h < 2; ++h) {
        const __bf16* wb = wlan + (size_t)((wv * 2 + h) * 18) * 1024;
        const __bf16* ah = arow + h * KHALF;
#pragma unroll
        for (int kt = 0; kt < 18; ++kt) {
            bf16x8 a0 = *(const bf16x8*)(ah + kt * 32 + quad * 8);
            bf16x8 b0 = *(const bf16x8*)(wb + kt * 1024);
            bf16x8 b1 = *(const bf16x8*)(wb + kt * 1024 + 512);
            acc0 = __builtin_amdgcn_mfma_f32_16x16x32_bf16(a0, b0, acc0, 0, 0, 0);
            acc1 = __builtin_amdgcn_mfma_f32_16x16x32_bf16(a0, b1, acc1, 0, 0, 0);
        }
    }

#pragma unroll
    for (int rr = 0; rr < 4; ++rr) {
        int m0 = quad * 4 + rr;          // pixel 0..15
        int ja = j0 + m0;
        out[((b * OC + o0) * HH + i) * WW + ja] = acc0[rr];
        out[((b * OC + o1) * HH + i) * WW + ja] = acc1[rr];
    }
}

extern "C" void kernel_launch(void* const* d_in, const int* in_sizes, int n_in,
                              void* d_out, int out_size, void* d_ws, size_t ws_size,
                              hipStream_t stream)
{
    const float* x  = (const float*)d_in[0];
    const float* cw = (const float*)d_in[1];
    const float* pw = (const float*)d_in[2];
    const float* pb = (const float*)d_in[3];
    const float* aw = (const float*)d_in[4];
    const float* ab = (const float*)d_in[5];
    float* out = (float*)d_out;

    char* ws = (char*)d_ws;
    float*  offp = (float*)ws;                        // 2*4*18*9216 = 663552 fp32
    float*  adp  = offp + BB * 4 * 18 * HWX;          // 2*4*3*9216  = 221184 fp32
    float*  wrep = adp + BB * 4 * 3 * HWX;            // 27648 fp32
    __bf16* wbf  = (__bf16*)(wrep + KTOT * 24);       // 147456 bf16 (16B-aligned)
    float*  xT   = (float*)(wbf + (size_t)KTOT * OC); // 2359296 fp32 (16B-aligned)
    // total ws use: ~13.4 MB

    prep_kernel<<<876, 256, 0, stream>>>(pw, aw, cw, x, wrep, wbf, xT);
    offsets_kernel<<<BB * 144 * 4, 512, 0, stream>>>(x, wrep, offp, adp);
    deform_kernel<<<NWG, 256, 0, stream>>>(xT, offp, adp, pb, ab, wbf, out);
}